// Round 2
// baseline (462.083 us; speedup 1.0000x reference)
//
#include <hip/hip_runtime.h>
#include <math.h>

#define LR 0.05f

typedef __attribute__((ext_vector_type(8))) short short8;
typedef __attribute__((ext_vector_type(4))) float f32x4;

#define MFMA16(a, b, c) __builtin_amdgcn_mfma_f32_16x16x32_bf16(a, b, c, 0, 0, 0)

__device__ __forceinline__ unsigned short f2bf(float v) {
  unsigned int u = __float_as_uint(v);
  u += 0x7fffu + ((u >> 16) & 1u);
  return (unsigned short)(u >> 16);
}

__device__ __forceinline__ void ce2(float& a, float& b, bool asc) {
  float lo = fminf(a, b), hi = fmaxf(a, b);
  a = asc ? lo : hi; b = asc ? hi : lo;
}

// ---------------- prep: build bf16 weight copies -----------------------------
__global__ __launch_bounds__(256) void prep_kernel(
    const float* __restrict__ W1a, const float* __restrict__ W1b,
    const float* __restrict__ W2a, const float* __restrict__ W2b,
    unsigned short* __restrict__ W2bfA, unsigned short* __restrict__ W2bfB,
    unsigned short* __restrict__ W2TbfA, unsigned short* __restrict__ W2TbfB,
    unsigned short* __restrict__ W1TbfA, unsigned short* __restrict__ W1TbfB,
    unsigned short* __restrict__ W1tailA, unsigned short* __restrict__ W1tailB)
{
  int i = blockIdx.x * 256 + threadIdx.x;
  if (i < 131072) {
    const float* W2 = (i >> 16) ? W2b : W2a;
    unsigned short* o = (i >> 16) ? W2bfB : W2bfA;
    int j = i & 65535;
    o[j] = f2bf(W2[j]);
  } else if (i < 262144) {
    int i2 = i - 131072;
    const float* W2 = (i2 >> 16) ? W2b : W2a;
    unsigned short* o = (i2 >> 16) ? W2TbfB : W2TbfA;
    int j = i2 & 65535;
    int n = j >> 8, k = j & 255;
    o[j] = f2bf(W2[k * 256 + n]);
  } else if (i < 278528) {
    int i2 = i - 262144;
    const float* W1 = (i2 >> 13) ? W1b : W1a;
    unsigned short* o = (i2 >> 13) ? W1TbfB : W1TbfA;
    int j = i2 & 8191;
    int n = j >> 5, k = j & 31;
    o[j] = (k < 23) ? f2bf(W1[k * 256 + n]) : (unsigned short)0;
  } else if (i < 286720) {
    int i2 = i - 278528;
    const float* W1 = (i2 >> 12) ? W1b : W1a;
    unsigned short* o = (i2 >> 12) ? W1tailB : W1tailA;
    int j = i2 & 4095;
    int d = j >> 8, tt = j & 255;
    o[j] = (d < 6) ? f2bf(W1[(17 + d) * 256 + tt]) : (unsigned short)0;
  }
}

// ---------------- fused: 5 x (score + SVGD) + epilogue, one block per batch --
// R1 changes vs 461us baseline (latency-bound: MfmaUtil 9.4, VALU 31.6, occ 23):
//  - median via halved multiset: sort 512 = {496 upper-tri, 16 zeros}; exact
//    median of 1024 = avg(sorted[255], sorted[256]) (full set = this set x2)
//  - sort elements live in 2 VGPRs; intra-wave stages (k=2..128) run in the
//    sel bubble; 3 cross-wave LDS stages merge with existing barriers
//  - d2s LDS matrix deleted; K phase recomputes dv from acur (reads it anyway)
//  - h1/h2 of both nets merged under single barriers; xsm update folded into
//    the acur-writeback slot.  Barriers: 16 -> 11 per step.
__global__ __launch_bounds__(256) void fused_kernel(
    const float* __restrict__ obs, const float* __restrict__ a0,
    const float* __restrict__ b1a, const float* __restrict__ b2a,
    const float* __restrict__ W3a, const float* __restrict__ b3a,
    const float* __restrict__ b1b, const float* __restrict__ b2b,
    const float* __restrict__ W3b, const float* __restrict__ b3b,
    const unsigned short* __restrict__ W2bfA, const unsigned short* __restrict__ W2bfB,
    const unsigned short* __restrict__ W2TbfA, const unsigned short* __restrict__ W2TbfB,
    const unsigned short* __restrict__ W1TbfA, const unsigned short* __restrict__ W1TbfB,
    const unsigned short* __restrict__ W1tailA, const unsigned short* __restrict__ W1tailB,
    float* __restrict__ out)
{
  __shared__ __align__(16) unsigned short buf0[32][264];  // h1a -> dh2c; sortA/B alias
  __shared__ __align__(16) unsigned short buf1[32][264];  // h1b -> dh1_m
  __shared__ __align__(16) unsigned short xsm[32][40];    // bf16 x (obs cols persist)
  __shared__ __align__(16) float upool[384];              // qpart[2][4][32] | redS[64][6]
  __shared__ float acur[32][6];
  __shared__ float Svv[32][6];
  __shared__ float XSsh[32];
  __shared__ float logps[32];
  __shared__ float asq[32];
  __shared__ int   selsh[32];
  __shared__ float medsh[2];

  float (*qpart)[4][32] = (float (*)[4][32])upool;
  float (*redS)[6] = (float (*)[6])upool;

  const int t = threadIdx.x;
  const int lane = t & 63, wv = t >> 6, quad = lane >> 4, l16 = lane & 15;
  const int b = blockIdx.x;
  const int base = b * 32;
  const int ctb = wv * 4;
  const long abase = (long)b * 192;

  float* sortA = (float*)&buf0[0][0];   // 512 floats
  float* sortB = sortA + 512;           // 512 floats
  const int eb = t * 2;                 // this thread's 2 sort elements

  // triangular index map for sort elements 2t, 2t+1 (step-invariant, packed)
  int packij = 0;
  {
    #pragma unroll
    for (int m = 0; m < 2; ++m) {
      int e = eb + m;
      int ii = 0, jj = 0;
      if (e < 496) {
        float sq = sqrtf(992.25f - 2.0f * (float)e);
        ii = (int)(31.5f - sq);
        if (e >= ((ii + 1) * (62 - ii)) / 2) ++ii;
        else if (e < (ii * (63 - ii)) / 2) --ii;
        jj = ii + 1 + (e - (ii * (63 - ii)) / 2);
      }
      packij |= (ii | (jj << 5)) << (m * 10);
    }
  }

  // ---- init ----
  if (t < 192) { int r = t / 6, d = t - r * 6; acur[r][d] = a0[abase + t]; }
  if (t < 32) {
    float s = 0.f;
    #pragma unroll
    for (int d = 0; d < 6; ++d) { float x0 = a0[abase + t * 6 + d]; s += x0 * x0; }
    asq[t] = s; logps[t] = 0.f;
  }
  for (int idx = t; idx < 32 * 40; idx += 256) {
    int r = idx / 40, k = idx - r * 40;
    float v = 0.f;
    if (k < 17) v = obs[(base + r) * 17 + k];
    else if (k < 23) v = a0[abase + r * 6 + (k - 17)];
    xsm[r][k] = f2bf(v);
  }
  __syncthreads();

  #pragma unroll 1
  for (int s = 0; s < 5; ++s) {
    // ---- sort element values (regs) from acur ----
    float sv0 = 0.f, sv1 = 0.f;
    {
      int i0 = packij & 31, j0 = (packij >> 5) & 31;
      int i1 = (packij >> 10) & 31, j1 = (packij >> 15) & 31;
      #pragma unroll
      for (int d = 0; d < 6; ++d) {
        float d0 = acur[i0][d] - acur[j0][d]; sv0 += d0 * d0;
        float d1 = acur[i1][d] - acur[j1][d]; sv1 += d1 * d1;
      }
    }

    // ================= h1 both nets =================
    unsigned int m1a_bits = 0, m1b_bits = 0, m2a_bits = 0, m2b_bits = 0;
    #pragma unroll 1
    for (int net = 0; net < 2; ++net) {
      const unsigned short* W1T = net ? W1TbfB : W1TbfA;
      const float* b1 = net ? b1b : b1a;
      unsigned short (*hbuf)[264] = net ? buf1 : buf0;
      unsigned int m1 = 0;
      short8 ax0 = *(const short8*)&xsm[l16][quad * 8];
      short8 ax1 = *(const short8*)&xsm[16 + l16][quad * 8];
      #pragma unroll
      for (int c = 0; c < 4; ++c) {
        int col = (ctb + c) * 16 + l16;
        short8 bw = *(const short8*)&W1T[col * 32 + quad * 8];
        f32x4 z = {0.f, 0.f, 0.f, 0.f};
        f32x4 h0 = MFMA16(ax0, bw, z);
        f32x4 h1v = MFMA16(ax1, bw, z);
        float b1v = b1[col];
        #pragma unroll
        for (int g = 0; g < 4; ++g) {
          float v0 = h0[g] + b1v;
          float v1 = h1v[g] + b1v;
          if (v0 > 0.f) m1 |= 1u << ((0 * 4 + c) * 4 + g);
          if (v1 > 0.f) m1 |= 1u << ((1 * 4 + c) * 4 + g);
          hbuf[quad * 4 + g][col] = (v0 > 0.f) ? f2bf(v0) : (unsigned short)0;
          hbuf[16 + quad * 4 + g][col] = (v1 > 0.f) ? f2bf(v1) : (unsigned short)0;
        }
      }
      if (net) m1b_bits = m1; else m1a_bits = m1;
    }
    __syncthreads();  // B1

    // ================= h2 both nets + qpart =================
    #pragma unroll 1
    for (int net = 0; net < 2; ++net) {
      const unsigned short* W2T = net ? W2TbfB : W2TbfA;
      const float* b2 = net ? b2b : b2a;
      const float* W3 = net ? W3b : W3a;
      unsigned short (*hbuf)[264] = net ? buf1 : buf0;

      float pq[2][4] = {{0.f, 0.f, 0.f, 0.f}, {0.f, 0.f, 0.f, 0.f}};
      unsigned int m2 = 0;
      #pragma unroll 1
      for (int hf = 0; hf < 2; ++hf) {
        f32x4 acc[2][2];
        acc[0][0] = acc[0][1] = acc[1][0] = acc[1][1] = (f32x4){0.f, 0.f, 0.f, 0.f};
        #pragma unroll 2
        for (int k = 0; k < 8; ++k) {
          short8 a0f = *(const short8*)&hbuf[l16][k * 32 + quad * 8];
          short8 a1f = *(const short8*)&hbuf[16 + l16][k * 32 + quad * 8];
          #pragma unroll
          for (int c = 0; c < 2; ++c) {
            int col = (ctb + hf * 2 + c) * 16 + l16;
            short8 bw = *(const short8*)&W2T[col * 256 + k * 32 + quad * 8];
            acc[0][c] = MFMA16(a0f, bw, acc[0][c]);
            acc[1][c] = MFMA16(a1f, bw, acc[1][c]);
          }
        }
        #pragma unroll
        for (int rt = 0; rt < 2; ++rt)
          #pragma unroll
          for (int c = 0; c < 2; ++c) {
            int cc = hf * 2 + c;
            int col = (ctb + cc) * 16 + l16;
            float b2v = b2[col], w3v = W3[col];
            #pragma unroll
            for (int g = 0; g < 4; ++g) {
              float v = acc[rt][c][g] + b2v;
              if (v > 0.f) {
                m2 |= 1u << ((rt * 4 + cc) * 4 + g);
                pq[rt][g] += v * w3v;
              }
            }
          }
      }
      if (net) m2b_bits = m2; else m2a_bits = m2;
      #pragma unroll
      for (int off = 8; off; off >>= 1) {
        #pragma unroll
        for (int rt = 0; rt < 2; ++rt)
          #pragma unroll
          for (int g = 0; g < 4; ++g)
            pq[rt][g] += __shfl_xor(pq[rt][g], off, 16);
      }
      if (l16 == 0) {
        #pragma unroll
        for (int rt = 0; rt < 2; ++rt)
          #pragma unroll
          for (int g = 0; g < 4; ++g)
            qpart[net][wv][rt * 16 + quad * 4 + g] = pq[rt][g];
      }
    }
    __syncthreads();  // B2

    // ---- sel (t<32) + intra-wave sort k=2..128 (barrier bubble filler) ----
    if (t < 32) {
      float qa = b3a[0], qb = b3b[0];
      #pragma unroll
      for (int w = 0; w < 4; ++w) { qa += qpart[0][w][t]; qb += qpart[1][w][t]; }
      selsh[t] = (qa <= qb) ? 0 : 1;
    }
    #pragma unroll
    for (int k = 2; k <= 128; k <<= 1) {
      #pragma unroll
      for (int j = k >> 1; j >= 2; j >>= 1) {
        int lm = j >> 1;
        bool km = (((eb & j) == 0) == ((eb & k) == 0));
        float p0 = __shfl_xor(sv0, lm);
        sv0 = km ? fminf(sv0, p0) : fmaxf(sv0, p0);
        float p1 = __shfl_xor(sv1, lm);
        sv1 = km ? fminf(sv1, p1) : fmaxf(sv1, p1);
      }
      ce2(sv0, sv1, ((eb & k) == 0));
    }
    __syncthreads();  // B3

    // ---- dh2c: single buffer, selected net only ----
    #pragma unroll
    for (int rt = 0; rt < 2; ++rt)
      #pragma unroll
      for (int c = 0; c < 4; ++c) {
        int col = (ctb + c) * 16 + l16;
        unsigned short w3abf = f2bf(W3a[col]);
        unsigned short w3bbf = f2bf(W3b[col]);
        #pragma unroll
        for (int g = 0; g < 4; ++g) {
          int row = rt * 16 + quad * 4 + g;
          int sl = selsh[row];
          int bit = (rt * 4 + c) * 4 + g;
          unsigned int mb = sl ? m2b_bits : m2a_bits;
          unsigned short wv3 = sl ? w3bbf : w3abf;
          buf0[row][col] = ((mb >> bit) & 1) ? wv3 : (unsigned short)0;
        }
      }
    __syncthreads();  // B4

    // ---- bwd: 4 one-col-tile passes; masked dh1 -> buf1 ----
    #pragma unroll 1
    for (int p = 0; p < 4; ++p) {
      int col = (ctb + p) * 16 + l16;
      f32x4 ba[2], bb[2];
      ba[0] = ba[1] = bb[0] = bb[1] = (f32x4){0.f, 0.f, 0.f, 0.f};
      #pragma unroll 2
      for (int k = 0; k < 8; ++k) {
        short8 bwA = *(const short8*)&W2bfA[col * 256 + k * 32 + quad * 8];
        short8 bwB = *(const short8*)&W2bfB[col * 256 + k * 32 + quad * 8];
        short8 a0d = *(const short8*)&buf0[l16][k * 32 + quad * 8];
        short8 a1d = *(const short8*)&buf0[16 + l16][k * 32 + quad * 8];
        ba[0] = MFMA16(a0d, bwA, ba[0]);
        bb[0] = MFMA16(a0d, bwB, bb[0]);
        ba[1] = MFMA16(a1d, bwA, ba[1]);
        bb[1] = MFMA16(a1d, bwB, bb[1]);
      }
      #pragma unroll
      for (int rt = 0; rt < 2; ++rt)
        #pragma unroll
        for (int g = 0; g < 4; ++g) {
          int row = rt * 16 + quad * 4 + g;
          int sl = selsh[row];
          float val = sl ? bb[rt][g] : ba[rt][g];
          unsigned int mb = sl ? m1b_bits : m1a_bits;
          int bit = (rt * 4 + p) * 4 + g;
          buf1[row][col] = ((mb >> bit) & 1) ? f2bf(val) : (unsigned short)0;
        }
    }
    __syncthreads();  // B5

    // ---- S (both nets from dh1) + sort stage1 write (buf0 now dead) ----
    {
      int net = wv >> 1, rt = wv & 1;
      const unsigned short* Wt = net ? W1tailB : W1tailA;
      f32x4 sacc = {0.f, 0.f, 0.f, 0.f};
      #pragma unroll 2
      for (int k = 0; k < 8; ++k) {
        short8 a = *(const short8*)&buf1[rt * 16 + l16][k * 32 + quad * 8];
        short8 bb2 = *(const short8*)&Wt[l16 * 256 + k * 32 + quad * 8];
        sacc = MFMA16(a, bb2, sacc);
      }
      if (l16 < 6) {
        #pragma unroll
        for (int g = 0; g < 4; ++g)
          redS[net * 32 + rt * 16 + quad * 4 + g][l16] = sacc[g];
      }
    }
    sortA[eb] = sv0; sortA[eb + 1] = sv1;
    __syncthreads();  // B6

    // ---- sort stage1 read (k=256, j=128) + tail + Svv fill + stage2 write --
    {
      bool km = (((eb & 128) == 0) == ((eb & 256) == 0));
      float p0 = sortA[eb ^ 128];
      float p1 = sortA[(eb ^ 128) + 1];
      sv0 = km ? fminf(sv0, p0) : fmaxf(sv0, p0);
      sv1 = km ? fminf(sv1, p1) : fmaxf(sv1, p1);
      #pragma unroll
      for (int j = 64; j >= 2; j >>= 1) {
        int lm = j >> 1;
        bool k2 = (((eb & j) == 0) == ((eb & 256) == 0));
        float q0 = __shfl_xor(sv0, lm);
        sv0 = k2 ? fminf(sv0, q0) : fmaxf(sv0, q0);
        float q1 = __shfl_xor(sv1, lm);
        sv1 = k2 ? fminf(sv1, q1) : fmaxf(sv1, q1);
      }
      ce2(sv0, sv1, ((eb & 256) == 0));
    }
    if (t < 192) { int r = t / 6, d = t - r * 6; Svv[r][d] = redS[selsh[r] * 32 + r][d]; }
    sortB[eb] = sv0; sortB[eb + 1] = sv1;
    __syncthreads();  // B7

    // ---- sort stage2 read (k=512, j=256) + XSsh + stage3 write ----
    {
      bool km = ((eb & 256) == 0);
      float p0 = sortB[eb ^ 256];
      float p1 = sortB[(eb ^ 256) + 1];
      sv0 = km ? fminf(sv0, p0) : fmaxf(sv0, p0);
      sv1 = km ? fminf(sv1, p1) : fmaxf(sv1, p1);
    }
    if (t < 32) {
      float sx = 0.f;
      #pragma unroll
      for (int d = 0; d < 6; ++d) sx += acur[t][d] * Svv[t][d];
      XSsh[t] = sx;
    }
    sortA[eb] = sv0; sortA[eb + 1] = sv1;
    __syncthreads();  // B8

    // ---- sort stage3 read (j=128) + final tail + median ----
    {
      bool km = ((eb & 128) == 0);
      float p0 = sortA[eb ^ 128];
      float p1 = sortA[(eb ^ 128) + 1];
      sv0 = km ? fminf(sv0, p0) : fmaxf(sv0, p0);
      sv1 = km ? fminf(sv1, p1) : fmaxf(sv1, p1);
      #pragma unroll
      for (int j = 64; j >= 2; j >>= 1) {
        int lm = j >> 1;
        bool k2 = ((eb & j) == 0);
        float q0 = __shfl_xor(sv0, lm);
        sv0 = k2 ? fminf(sv0, q0) : fmaxf(sv0, q0);
        float q1 = __shfl_xor(sv1, lm);
        sv1 = k2 ? fminf(sv1, q1) : fmaxf(sv1, q1);
      }
      ce2(sv0, sv1, true);
    }
    if (t == 127) medsh[0] = sv1;  // element 255
    if (t == 128) medsh[1] = sv0;  // element 256
    __syncthreads();  // B9

    // ================= K row-sums + update (dv recomputed from acur) ========
    float med = 0.5f * (medsh[0] + medsh[1]);
    float g = 1.0f / (2.0f * (med / logf(33.0f)) + 1e-8f);

    const int i = t >> 3, l = t & 7;
    float ai0 = acur[i][0], ai1 = acur[i][1], ai2 = acur[i][2];
    float ai3 = acur[i][3], ai4 = acur[i][4], ai5 = acur[i][5];
    float ks0=0,ks1=0,ks2=0,ks3=0,ks4=0,ks5=0;
    float kx0=0,kx1=0,kx2=0,kx3=0,kx4=0,kx5=0;
    float krow=0.f, kd2=0.f, kxs=0.f;
    #pragma unroll
    for (int jj = 0; jj < 4; ++jj) {
      int j = l + 8 * jj;
      float aj0 = acur[j][0], aj1 = acur[j][1], aj2 = acur[j][2];
      float aj3 = acur[j][3], aj4 = acur[j][4], aj5 = acur[j][5];
      float dv = 0.f, df;
      df = ai0 - aj0; dv += df * df;
      df = ai1 - aj1; dv += df * df;
      df = ai2 - aj2; dv += df * df;
      df = ai3 - aj3; dv += df * df;
      df = ai4 - aj4; dv += df * df;
      df = ai5 - aj5; dv += df * df;
      float kv = expf(-g * dv);
      krow += kv; kd2 += kv * dv; kxs += kv * XSsh[j];
      ks0 += kv * Svv[j][0]; kx0 += kv * aj0;
      ks1 += kv * Svv[j][1]; kx1 += kv * aj1;
      ks2 += kv * Svv[j][2]; kx2 += kv * aj2;
      ks3 += kv * Svv[j][3]; kx3 += kv * aj3;
      ks4 += kv * Svv[j][4]; kx4 += kv * aj4;
      ks5 += kv * Svv[j][5]; kx5 += kv * aj5;
    }
    #pragma unroll
    for (int off = 4; off > 0; off >>= 1) {
      krow += __shfl_down(krow, off, 8);
      kd2  += __shfl_down(kd2,  off, 8);
      kxs  += __shfl_down(kxs,  off, 8);
      ks0 += __shfl_down(ks0, off, 8); kx0 += __shfl_down(kx0, off, 8);
      ks1 += __shfl_down(ks1, off, 8); kx1 += __shfl_down(kx1, off, 8);
      ks2 += __shfl_down(ks2, off, 8); kx2 += __shfl_down(kx2, off, 8);
      ks3 += __shfl_down(ks3, off, 8); kx3 += __shfl_down(kx3, off, 8);
      ks4 += __shfl_down(ks4, off, 8); kx4 += __shfl_down(kx4, off, 8);
      ks5 += __shfl_down(ks5, off, 8); kx5 += __shfl_down(kx5, off, 8);
    }
    float an0=0,an1=0,an2=0,an3=0,an4=0,an5=0, lpnew=0;
    if (l == 0) {
      const float inv_n = 1.0f / 32.0f;
      float t1sum = 0.f, p;
      p = (ks0 + 2.f*g*(ai0*krow - kx0)) * inv_n; an0 = ai0 + LR * p; t1sum += ai0 * ks0;
      p = (ks1 + 2.f*g*(ai1*krow - kx1)) * inv_n; an1 = ai1 + LR * p; t1sum += ai1 * ks1;
      p = (ks2 + 2.f*g*(ai2*krow - kx2)) * inv_n; an2 = ai2 + LR * p; t1sum += ai2 * ks2;
      p = (ks3 + 2.f*g*(ai3*krow - kx3)) * inv_n; an3 = ai3 + LR * p; t1sum += ai3 * ks3;
      p = (ks4 + 2.f*g*(ai4*krow - kx4)) * inv_n; an4 = ai4 + LR * p; t1sum += ai4 * ks4;
      p = (ks5 + 2.f*g*(ai5*krow - kx5)) * inv_n; an5 = ai5 + LR * p; t1sum += ai5 * ks5;
      float term1 = (-2.f * g / 31.f) * (t1sum - kxs);
      float term2 = (-2.f * g / 31.f) * (2.f * g * kd2 - 6.f * (krow - 1.f));
      lpnew = logps[i] - LR * (term1 + term2);
    }
    __syncthreads();  // B10
    if (l == 0) {
      acur[i][0] = an0; acur[i][1] = an1; acur[i][2] = an2;
      acur[i][3] = an3; acur[i][4] = an4; acur[i][5] = an5;
      logps[i] = lpnew;
      xsm[i][17] = f2bf(an0); xsm[i][18] = f2bf(an1); xsm[i][19] = f2bf(an2);
      xsm[i][20] = f2bf(an3); xsm[i][21] = f2bf(an4); xsm[i][22] = f2bf(an5);
    }
    __syncthreads();  // B11
  }

  // ================= epilogue =================
  if (t < 192) { int r = t / 6, d = t - r * 6; out[abase + t] = tanhf(acur[r][d]); }
  if (t < 32) {
    float st = 0.f;
    #pragma unroll
    for (int d = 0; d < 6; ++d) {
      float x = acur[t][d];
      float z = -2.f * x;
      float sp = fmaxf(z, 0.f) + log1pf(expf(-fabsf(z)));
      st += 2.f * (0.69314718056f - x - sp);
    }
    float lpn = -3.0f * logf(1.88495559215f) - (0.5f / 0.3f) * asq[t];
    XSsh[t] = lpn + logps[t] - st;
  }
  __syncthreads();
  if (t == 0) {
    float s = 0.f;
    #pragma unroll
    for (int n = 0; n < 32; ++n) s += XSsh[n];
    out[196608 + b] = s * (1.0f / 32.0f);
  }
}

extern "C" void kernel_launch(void* const* d_in, const int* in_sizes, int n_in,
                              void* d_out, int out_size, void* d_ws, size_t ws_size,
                              hipStream_t stream) {
  const float* obs  = (const float*)d_in[0];
  const float* a0   = (const float*)d_in[1];
  const float* q1W1 = (const float*)d_in[2];
  const float* q1b1 = (const float*)d_in[3];
  const float* q1W2 = (const float*)d_in[4];
  const float* q1b2 = (const float*)d_in[5];
  const float* q1W3 = (const float*)d_in[6];
  const float* q1b3 = (const float*)d_in[7];
  const float* q2W1 = (const float*)d_in[8];
  const float* q2b1 = (const float*)d_in[9];
  const float* q2W2 = (const float*)d_in[10];
  const float* q2b2 = (const float*)d_in[11];
  const float* q2W3 = (const float*)d_in[12];
  const float* q2b3 = (const float*)d_in[13];

  unsigned short* wsu = (unsigned short*)d_ws;
  unsigned short* W2bfA  = wsu;
  unsigned short* W2bfB  = W2bfA + 65536;
  unsigned short* W2TbfA = W2bfB + 65536;
  unsigned short* W2TbfB = W2TbfA + 65536;
  unsigned short* W1TbfA = W2TbfB + 65536;
  unsigned short* W1TbfB = W1TbfA + 8192;
  unsigned short* W1tailA = W1TbfB + 8192;
  unsigned short* W1tailB = W1tailA + 4096;
  float* out  = (float*)d_out;

  prep_kernel<<<1120, 256, 0, stream>>>(q1W1, q2W1, q1W2, q2W2,
      W2bfA, W2bfB, W2TbfA, W2TbfB, W1TbfA, W1TbfB, W1tailA, W1tailB);

  fused_kernel<<<1024, 256, 0, stream>>>(obs, a0,
      q1b1, q1b2, q1W3, q1b3,
      q2b1, q2b2, q2W3, q2b3,
      W2bfA, W2bfB, W2TbfA, W2TbfB, W1TbfA, W1TbfB, W1tailA, W1tailB,
      out);
}

// Round 3
// 395.902 us; speedup vs baseline: 1.1672x; 1.1672x over previous
//
#include <hip/hip_runtime.h>
#include <math.h>

#define LR 0.05f

typedef __attribute__((ext_vector_type(8))) short short8;
typedef __attribute__((ext_vector_type(4))) float f32x4;

#define MFMA16(a, b, c) __builtin_amdgcn_mfma_f32_16x16x32_bf16(a, b, c, 0, 0, 0)

__device__ __forceinline__ unsigned short f2bf(float v) {
  unsigned int u = __float_as_uint(v);
  u += 0x7fffu + ((u >> 16) & 1u);
  return (unsigned short)(u >> 16);
}

__device__ __forceinline__ void ce2(float& a, float& b, bool asc) {
  float lo = fminf(a, b), hi = fmaxf(a, b);
  a = asc ? lo : hi; b = asc ? hi : lo;
}

// ---------------- prep: build FRAGMENT-ORDERED bf16 weight copies ------------
// R2: all B-operand tiles stored so one wave-load = one contiguous 1KB block:
//   frag[tile*512 + l16*32 + quad*8 + e]  (tile = ct*K + k)
// replaces 512B-strided per-lane reads (16 scattered lines -> 16 consecutive).
__global__ __launch_bounds__(256) void prep_kernel(
    const float* __restrict__ W1a, const float* __restrict__ W1b,
    const float* __restrict__ W2a, const float* __restrict__ W2b,
    unsigned short* __restrict__ W2bfA, unsigned short* __restrict__ W2bfB,
    unsigned short* __restrict__ W2TbfA, unsigned short* __restrict__ W2TbfB,
    unsigned short* __restrict__ W1TbfA, unsigned short* __restrict__ W1TbfB,
    unsigned short* __restrict__ W1tailA, unsigned short* __restrict__ W1tailB)
{
  int i = blockIdx.x * 256 + threadIdx.x;
  if (i < 131072) {
    // W2 fragment (bwd B): frag[(ct*8+k)*512 + l16*32 + rem] = W2[(ct*16+l16)*256 + k*32+rem]
    const float* W2 = (i >> 16) ? W2b : W2a;
    unsigned short* o = (i >> 16) ? W2bfB : W2bfA;
    int j = i & 65535;
    int tile = j >> 9, within = j & 511;
    int l16 = within >> 5, rem = within & 31;
    int ct = tile >> 3, k = tile & 7;
    o[j] = f2bf(W2[(ct * 16 + l16) * 256 + k * 32 + rem]);
  } else if (i < 262144) {
    // W2T fragment (h2 B): frag[(ct*8+k)*512 + l16*32 + rem] = W2[(k*32+rem)*256 + ct*16+l16]
    int i2 = i - 131072;
    const float* W2 = (i2 >> 16) ? W2b : W2a;
    unsigned short* o = (i2 >> 16) ? W2TbfB : W2TbfA;
    int j = i2 & 65535;
    int tile = j >> 9, within = j & 511;
    int l16 = within >> 5, rem = within & 31;
    int ct = tile >> 3, k = tile & 7;
    o[j] = f2bf(W2[(k * 32 + rem) * 256 + ct * 16 + l16]);
  } else if (i < 278528) {
    // W1T fragment (h1 B): frag[ct*512 + l16*32 + rem] = (rem<23)? W1[rem*256 + ct*16+l16] : 0
    int i2 = i - 262144;
    const float* W1 = (i2 >> 13) ? W1b : W1a;
    unsigned short* o = (i2 >> 13) ? W1TbfB : W1TbfA;
    int j = i2 & 8191;
    int ct = j >> 9, within = j & 511;
    int l16 = within >> 5, rem = within & 31;
    o[j] = (rem < 23) ? f2bf(W1[rem * 256 + ct * 16 + l16]) : (unsigned short)0;
  } else if (i < 286720) {
    // W1tail fragment (S B): frag[k*512 + l16*32 + rem] = (l16<6)? W1[(17+l16)*256 + k*32+rem] : 0
    int i2 = i - 278528;
    const float* W1 = (i2 >> 12) ? W1b : W1a;
    unsigned short* o = (i2 >> 12) ? W1tailB : W1tailA;
    int j = i2 & 4095;
    int k = j >> 9, within = j & 511;
    int l16 = within >> 5, rem = within & 31;
    o[j] = (l16 < 6) ? f2bf(W1[(17 + l16) * 256 + k * 32 + rem]) : (unsigned short)0;
  }
}

// ---------------- fused: 5 x (score + SVGD) + epilogue, one block per batch --
// R2 vs R1 (null) post-mortem: time is TA/L2 + LDS-read bound in GEMM phases.
//  - fragment-ordered weights: every B-load is a contiguous 1KB wave-load
//    (addr = tile*1024B + wfrag, wfrag lane-invariant across all loads)
//  - h2: hf-passes merged (acc[2][4], 32 reg) -> A-fragment LDS reads halved
//  - bwd: col-tiles paired (2x2, acc 32 reg)  -> dh2c LDS reads halved
//  - math/accumulation order unchanged -> bit-identical results
__global__ __launch_bounds__(256, 4) void fused_kernel(
    const float* __restrict__ obs, const float* __restrict__ a0,
    const float* __restrict__ b1a, const float* __restrict__ b2a,
    const float* __restrict__ W3a, const float* __restrict__ b3a,
    const float* __restrict__ b1b, const float* __restrict__ b2b,
    const float* __restrict__ W3b, const float* __restrict__ b3b,
    const unsigned short* __restrict__ W2bfA, const unsigned short* __restrict__ W2bfB,
    const unsigned short* __restrict__ W2TbfA, const unsigned short* __restrict__ W2TbfB,
    const unsigned short* __restrict__ W1TbfA, const unsigned short* __restrict__ W1TbfB,
    const unsigned short* __restrict__ W1tailA, const unsigned short* __restrict__ W1tailB,
    float* __restrict__ out)
{
  __shared__ __align__(16) unsigned short buf0[32][264];  // h1a -> dh2c; sortA/B alias
  __shared__ __align__(16) unsigned short buf1[32][264];  // h1b -> dh1_m
  __shared__ __align__(16) unsigned short xsm[32][40];    // bf16 x (obs cols persist)
  __shared__ __align__(16) float upool[384];              // qpart[2][4][32] | redS[64][6]
  __shared__ float acur[32][6];
  __shared__ float Svv[32][6];
  __shared__ float XSsh[32];
  __shared__ float logps[32];
  __shared__ float asq[32];
  __shared__ int   selsh[32];
  __shared__ float medsh[2];

  float (*qpart)[4][32] = (float (*)[4][32])upool;
  float (*redS)[6] = (float (*)[6])upool;

  const int t = threadIdx.x;
  const int lane = t & 63, wv = t >> 6, quad = lane >> 4, l16 = lane & 15;
  const int b = blockIdx.x;
  const int base = b * 32;
  const int ctb = wv * 4;
  const long abase = (long)b * 192;
  const int wfrag = l16 * 32 + quad * 8;   // lane's short-offset within a 1KB tile

  float* sortA = (float*)&buf0[0][0];   // 512 floats
  float* sortB = sortA + 512;           // 512 floats
  const int eb = t * 2;                 // this thread's 2 sort elements

  // triangular index map for sort elements 2t, 2t+1 (step-invariant, packed)
  int packij = 0;
  {
    #pragma unroll
    for (int m = 0; m < 2; ++m) {
      int e = eb + m;
      int ii = 0, jj = 0;
      if (e < 496) {
        float sq = sqrtf(992.25f - 2.0f * (float)e);
        ii = (int)(31.5f - sq);
        if (e >= ((ii + 1) * (62 - ii)) / 2) ++ii;
        else if (e < (ii * (63 - ii)) / 2) --ii;
        jj = ii + 1 + (e - (ii * (63 - ii)) / 2);
      }
      packij |= (ii | (jj << 5)) << (m * 10);
    }
  }

  // ---- init ----
  if (t < 192) { int r = t / 6, d = t - r * 6; acur[r][d] = a0[abase + t]; }
  if (t < 32) {
    float s = 0.f;
    #pragma unroll
    for (int d = 0; d < 6; ++d) { float x0 = a0[abase + t * 6 + d]; s += x0 * x0; }
    asq[t] = s; logps[t] = 0.f;
  }
  for (int idx = t; idx < 32 * 40; idx += 256) {
    int r = idx / 40, k = idx - r * 40;
    float v = 0.f;
    if (k < 17) v = obs[(base + r) * 17 + k];
    else if (k < 23) v = a0[abase + r * 6 + (k - 17)];
    xsm[r][k] = f2bf(v);
  }
  __syncthreads();

  #pragma unroll 1
  for (int s = 0; s < 5; ++s) {
    // ---- sort element values (regs) from acur ----
    float sv0 = 0.f, sv1 = 0.f;
    {
      int i0 = packij & 31, j0 = (packij >> 5) & 31;
      int i1 = (packij >> 10) & 31, j1 = (packij >> 15) & 31;
      #pragma unroll
      for (int d = 0; d < 6; ++d) {
        float d0 = acur[i0][d] - acur[j0][d]; sv0 += d0 * d0;
        float d1 = acur[i1][d] - acur[j1][d]; sv1 += d1 * d1;
      }
    }

    // ================= h1 both nets =================
    unsigned int m1a_bits = 0, m1b_bits = 0, m2a_bits = 0, m2b_bits = 0;
    #pragma unroll 1
    for (int net = 0; net < 2; ++net) {
      const unsigned short* W1T = net ? W1TbfB : W1TbfA;
      const float* b1 = net ? b1b : b1a;
      unsigned short (*hbuf)[264] = net ? buf1 : buf0;
      unsigned int m1 = 0;
      short8 ax0 = *(const short8*)&xsm[l16][quad * 8];
      short8 ax1 = *(const short8*)&xsm[16 + l16][quad * 8];
      #pragma unroll
      for (int c = 0; c < 4; ++c) {
        short8 bw = *(const short8*)&W1T[(ctb + c) * 512 + wfrag];
        int col = (ctb + c) * 16 + l16;
        f32x4 z = {0.f, 0.f, 0.f, 0.f};
        f32x4 h0 = MFMA16(ax0, bw, z);
        f32x4 h1v = MFMA16(ax1, bw, z);
        float b1v = b1[col];
        #pragma unroll
        for (int g = 0; g < 4; ++g) {
          float v0 = h0[g] + b1v;
          float v1 = h1v[g] + b1v;
          if (v0 > 0.f) m1 |= 1u << ((0 * 4 + c) * 4 + g);
          if (v1 > 0.f) m1 |= 1u << ((1 * 4 + c) * 4 + g);
          hbuf[quad * 4 + g][col] = (v0 > 0.f) ? f2bf(v0) : (unsigned short)0;
          hbuf[16 + quad * 4 + g][col] = (v1 > 0.f) ? f2bf(v1) : (unsigned short)0;
        }
      }
      if (net) m1b_bits = m1; else m1a_bits = m1;
    }
    __syncthreads();  // B1

    // ================= h2 both nets + qpart (hf merged: acc[2][4]) ==========
    #pragma unroll 1
    for (int net = 0; net < 2; ++net) {
      const unsigned short* W2T = net ? W2TbfB : W2TbfA;
      const float* b2 = net ? b2b : b2a;
      const float* W3 = net ? W3b : W3a;
      unsigned short (*hbuf)[264] = net ? buf1 : buf0;

      f32x4 acc[2][4];
      #pragma unroll
      for (int rt = 0; rt < 2; ++rt)
        #pragma unroll
        for (int cc = 0; cc < 4; ++cc) acc[rt][cc] = (f32x4){0.f, 0.f, 0.f, 0.f};

      #pragma unroll 2
      for (int k = 0; k < 8; ++k) {
        short8 a0f = *(const short8*)&hbuf[l16][k * 32 + quad * 8];
        short8 a1f = *(const short8*)&hbuf[16 + l16][k * 32 + quad * 8];
        #pragma unroll
        for (int cc = 0; cc < 4; ++cc) {
          short8 bw = *(const short8*)&W2T[(ctb + cc) * 4096 + k * 512 + wfrag];
          acc[0][cc] = MFMA16(a0f, bw, acc[0][cc]);
          acc[1][cc] = MFMA16(a1f, bw, acc[1][cc]);
        }
      }

      float pq[2][4] = {{0.f, 0.f, 0.f, 0.f}, {0.f, 0.f, 0.f, 0.f}};
      unsigned int m2 = 0;
      #pragma unroll
      for (int rt = 0; rt < 2; ++rt)
        #pragma unroll
        for (int cc = 0; cc < 4; ++cc) {
          int col = (ctb + cc) * 16 + l16;
          float b2v = b2[col], w3v = W3[col];
          #pragma unroll
          for (int g = 0; g < 4; ++g) {
            float v = acc[rt][cc][g] + b2v;
            if (v > 0.f) {
              m2 |= 1u << ((rt * 4 + cc) * 4 + g);
              pq[rt][g] += v * w3v;
            }
          }
        }
      if (net) m2b_bits = m2; else m2a_bits = m2;
      #pragma unroll
      for (int off = 8; off; off >>= 1) {
        #pragma unroll
        for (int rt = 0; rt < 2; ++rt)
          #pragma unroll
          for (int g = 0; g < 4; ++g)
            pq[rt][g] += __shfl_xor(pq[rt][g], off, 16);
      }
      if (l16 == 0) {
        #pragma unroll
        for (int rt = 0; rt < 2; ++rt)
          #pragma unroll
          for (int g = 0; g < 4; ++g)
            qpart[net][wv][rt * 16 + quad * 4 + g] = pq[rt][g];
      }
    }
    __syncthreads();  // B2

    // ---- sel (t<32) + intra-wave sort k=2..128 (barrier bubble filler) ----
    if (t < 32) {
      float qa = b3a[0], qb = b3b[0];
      #pragma unroll
      for (int w = 0; w < 4; ++w) { qa += qpart[0][w][t]; qb += qpart[1][w][t]; }
      selsh[t] = (qa <= qb) ? 0 : 1;
    }
    #pragma unroll
    for (int k = 2; k <= 128; k <<= 1) {
      #pragma unroll
      for (int j = k >> 1; j >= 2; j >>= 1) {
        int lm = j >> 1;
        bool km = (((eb & j) == 0) == ((eb & k) == 0));
        float p0 = __shfl_xor(sv0, lm);
        sv0 = km ? fminf(sv0, p0) : fmaxf(sv0, p0);
        float p1 = __shfl_xor(sv1, lm);
        sv1 = km ? fminf(sv1, p1) : fmaxf(sv1, p1);
      }
      ce2(sv0, sv1, ((eb & k) == 0));
    }
    __syncthreads();  // B3

    // ---- dh2c: single buffer, selected net only ----
    #pragma unroll
    for (int rt = 0; rt < 2; ++rt)
      #pragma unroll
      for (int c = 0; c < 4; ++c) {
        int col = (ctb + c) * 16 + l16;
        unsigned short w3abf = f2bf(W3a[col]);
        unsigned short w3bbf = f2bf(W3b[col]);
        #pragma unroll
        for (int g = 0; g < 4; ++g) {
          int row = rt * 16 + quad * 4 + g;
          int sl = selsh[row];
          int bit = (rt * 4 + c) * 4 + g;
          unsigned int mb = sl ? m2b_bits : m2a_bits;
          unsigned short wv3 = sl ? w3bbf : w3abf;
          buf0[row][col] = ((mb >> bit) & 1) ? wv3 : (unsigned short)0;
        }
      }
    __syncthreads();  // B4

    // ---- bwd: 2 passes of paired col-tiles; masked dh1 -> buf1 ----
    #pragma unroll 1
    for (int pp = 0; pp < 2; ++pp) {
      f32x4 aA[2][2], aB[2][2];   // [pi][rt]
      #pragma unroll
      for (int pi = 0; pi < 2; ++pi) {
        aA[pi][0] = aA[pi][1] = (f32x4){0.f, 0.f, 0.f, 0.f};
        aB[pi][0] = aB[pi][1] = (f32x4){0.f, 0.f, 0.f, 0.f};
      }
      #pragma unroll 2
      for (int k = 0; k < 8; ++k) {
        short8 a0d = *(const short8*)&buf0[l16][k * 32 + quad * 8];
        short8 a1d = *(const short8*)&buf0[16 + l16][k * 32 + quad * 8];
        #pragma unroll
        for (int pi = 0; pi < 2; ++pi) {
          int p = pp * 2 + pi;
          short8 bwA = *(const short8*)&W2bfA[(ctb + p) * 4096 + k * 512 + wfrag];
          short8 bwB = *(const short8*)&W2bfB[(ctb + p) * 4096 + k * 512 + wfrag];
          aA[pi][0] = MFMA16(a0d, bwA, aA[pi][0]);
          aB[pi][0] = MFMA16(a0d, bwB, aB[pi][0]);
          aA[pi][1] = MFMA16(a1d, bwA, aA[pi][1]);
          aB[pi][1] = MFMA16(a1d, bwB, aB[pi][1]);
        }
      }
      #pragma unroll
      for (int pi = 0; pi < 2; ++pi) {
        int p = pp * 2 + pi;
        int col = (ctb + p) * 16 + l16;
        #pragma unroll
        for (int rt = 0; rt < 2; ++rt)
          #pragma unroll
          for (int g = 0; g < 4; ++g) {
            int row = rt * 16 + quad * 4 + g;
            int sl = selsh[row];
            float val = sl ? aB[pi][rt][g] : aA[pi][rt][g];
            unsigned int mb = sl ? m1b_bits : m1a_bits;
            int bit = (rt * 4 + p) * 4 + g;
            buf1[row][col] = ((mb >> bit) & 1) ? f2bf(val) : (unsigned short)0;
          }
      }
    }
    __syncthreads();  // B5

    // ---- S (both nets from dh1) + sort stage1 write (buf0 now dead) ----
    {
      int net = wv >> 1, rt = wv & 1;
      const unsigned short* Wt = net ? W1tailB : W1tailA;
      f32x4 sacc = {0.f, 0.f, 0.f, 0.f};
      #pragma unroll 2
      for (int k = 0; k < 8; ++k) {
        short8 a = *(const short8*)&buf1[rt * 16 + l16][k * 32 + quad * 8];
        short8 bb2 = *(const short8*)&Wt[k * 512 + wfrag];
        sacc = MFMA16(a, bb2, sacc);
      }
      if (l16 < 6) {
        #pragma unroll
        for (int g = 0; g < 4; ++g)
          redS[net * 32 + rt * 16 + quad * 4 + g][l16] = sacc[g];
      }
    }
    sortA[eb] = sv0; sortA[eb + 1] = sv1;
    __syncthreads();  // B6

    // ---- sort stage1 read (k=256, j=128) + tail + Svv fill + stage2 write --
    {
      bool km = (((eb & 128) == 0) == ((eb & 256) == 0));
      float p0 = sortA[eb ^ 128];
      float p1 = sortA[(eb ^ 128) + 1];
      sv0 = km ? fminf(sv0, p0) : fmaxf(sv0, p0);
      sv1 = km ? fminf(sv1, p1) : fmaxf(sv1, p1);
      #pragma unroll
      for (int j = 64; j >= 2; j >>= 1) {
        int lm = j >> 1;
        bool k2 = (((eb & j) == 0) == ((eb & 256) == 0));
        float q0 = __shfl_xor(sv0, lm);
        sv0 = k2 ? fminf(sv0, q0) : fmaxf(sv0, q0);
        float q1 = __shfl_xor(sv1, lm);
        sv1 = k2 ? fminf(sv1, q1) : fmaxf(sv1, q1);
      }
      ce2(sv0, sv1, ((eb & 256) == 0));
    }
    if (t < 192) { int r = t / 6, d = t - r * 6; Svv[r][d] = redS[selsh[r] * 32 + r][d]; }
    sortB[eb] = sv0; sortB[eb + 1] = sv1;
    __syncthreads();  // B7

    // ---- sort stage2 read (k=512, j=256) + XSsh + stage3 write ----
    {
      bool km = ((eb & 256) == 0);
      float p0 = sortB[eb ^ 256];
      float p1 = sortB[(eb ^ 256) + 1];
      sv0 = km ? fminf(sv0, p0) : fmaxf(sv0, p0);
      sv1 = km ? fminf(sv1, p1) : fmaxf(sv1, p1);
    }
    if (t < 32) {
      float sx = 0.f;
      #pragma unroll
      for (int d = 0; d < 6; ++d) sx += acur[t][d] * Svv[t][d];
      XSsh[t] = sx;
    }
    sortA[eb] = sv0; sortA[eb + 1] = sv1;
    __syncthreads();  // B8

    // ---- sort stage3 read (j=128) + final tail + median ----
    {
      bool km = ((eb & 128) == 0);
      float p0 = sortA[eb ^ 128];
      float p1 = sortA[(eb ^ 128) + 1];
      sv0 = km ? fminf(sv0, p0) : fmaxf(sv0, p0);
      sv1 = km ? fminf(sv1, p1) : fmaxf(sv1, p1);
      #pragma unroll
      for (int j = 64; j >= 2; j >>= 1) {
        int lm = j >> 1;
        bool k2 = ((eb & j) == 0);
        float q0 = __shfl_xor(sv0, lm);
        sv0 = k2 ? fminf(sv0, q0) : fmaxf(sv0, q0);
        float q1 = __shfl_xor(sv1, lm);
        sv1 = k2 ? fminf(sv1, q1) : fmaxf(sv1, q1);
      }
      ce2(sv0, sv1, true);
    }
    if (t == 127) medsh[0] = sv1;  // element 255
    if (t == 128) medsh[1] = sv0;  // element 256
    __syncthreads();  // B9

    // ================= K row-sums + update (dv recomputed from acur) ========
    float med = 0.5f * (medsh[0] + medsh[1]);
    float g = 1.0f / (2.0f * (med / logf(33.0f)) + 1e-8f);

    const int i = t >> 3, l = t & 7;
    float ai0 = acur[i][0], ai1 = acur[i][1], ai2 = acur[i][2];
    float ai3 = acur[i][3], ai4 = acur[i][4], ai5 = acur[i][5];
    float ks0=0,ks1=0,ks2=0,ks3=0,ks4=0,ks5=0;
    float kx0=0,kx1=0,kx2=0,kx3=0,kx4=0,kx5=0;
    float krow=0.f, kd2=0.f, kxs=0.f;
    #pragma unroll
    for (int jj = 0; jj < 4; ++jj) {
      int j = l + 8 * jj;
      float aj0 = acur[j][0], aj1 = acur[j][1], aj2 = acur[j][2];
      float aj3 = acur[j][3], aj4 = acur[j][4], aj5 = acur[j][5];
      float dv = 0.f, df;
      df = ai0 - aj0; dv += df * df;
      df = ai1 - aj1; dv += df * df;
      df = ai2 - aj2; dv += df * df;
      df = ai3 - aj3; dv += df * df;
      df = ai4 - aj4; dv += df * df;
      df = ai5 - aj5; dv += df * df;
      float kv = expf(-g * dv);
      krow += kv; kd2 += kv * dv; kxs += kv * XSsh[j];
      ks0 += kv * Svv[j][0]; kx0 += kv * aj0;
      ks1 += kv * Svv[j][1]; kx1 += kv * aj1;
      ks2 += kv * Svv[j][2]; kx2 += kv * aj2;
      ks3 += kv * Svv[j][3]; kx3 += kv * aj3;
      ks4 += kv * Svv[j][4]; kx4 += kv * aj4;
      ks5 += kv * Svv[j][5]; kx5 += kv * aj5;
    }
    #pragma unroll
    for (int off = 4; off > 0; off >>= 1) {
      krow += __shfl_down(krow, off, 8);
      kd2  += __shfl_down(kd2,  off, 8);
      kxs  += __shfl_down(kxs,  off, 8);
      ks0 += __shfl_down(ks0, off, 8); kx0 += __shfl_down(kx0, off, 8);
      ks1 += __shfl_down(ks1, off, 8); kx1 += __shfl_down(kx1, off, 8);
      ks2 += __shfl_down(ks2, off, 8); kx2 += __shfl_down(kx2, off, 8);
      ks3 += __shfl_down(ks3, off, 8); kx3 += __shfl_down(kx3, off, 8);
      ks4 += __shfl_down(ks4, off, 8); kx4 += __shfl_down(kx4, off, 8);
      ks5 += __shfl_down(ks5, off, 8); kx5 += __shfl_down(kx5, off, 8);
    }
    float an0=0,an1=0,an2=0,an3=0,an4=0,an5=0, lpnew=0;
    if (l == 0) {
      const float inv_n = 1.0f / 32.0f;
      float t1sum = 0.f, p;
      p = (ks0 + 2.f*g*(ai0*krow - kx0)) * inv_n; an0 = ai0 + LR * p; t1sum += ai0 * ks0;
      p = (ks1 + 2.f*g*(ai1*krow - kx1)) * inv_n; an1 = ai1 + LR * p; t1sum += ai1 * ks1;
      p = (ks2 + 2.f*g*(ai2*krow - kx2)) * inv_n; an2 = ai2 + LR * p; t1sum += ai2 * ks2;
      p = (ks3 + 2.f*g*(ai3*krow - kx3)) * inv_n; an3 = ai3 + LR * p; t1sum += ai3 * ks3;
      p = (ks4 + 2.f*g*(ai4*krow - kx4)) * inv_n; an4 = ai4 + LR * p; t1sum += ai4 * ks4;
      p = (ks5 + 2.f*g*(ai5*krow - kx5)) * inv_n; an5 = ai5 + LR * p; t1sum += ai5 * ks5;
      float term1 = (-2.f * g / 31.f) * (t1sum - kxs);
      float term2 = (-2.f * g / 31.f) * (2.f * g * kd2 - 6.f * (krow - 1.f));
      lpnew = logps[i] - LR * (term1 + term2);
    }
    __syncthreads();  // B10
    if (l == 0) {
      acur[i][0] = an0; acur[i][1] = an1; acur[i][2] = an2;
      acur[i][3] = an3; acur[i][4] = an4; acur[i][5] = an5;
      logps[i] = lpnew;
      xsm[i][17] = f2bf(an0); xsm[i][18] = f2bf(an1); xsm[i][19] = f2bf(an2);
      xsm[i][20] = f2bf(an3); xsm[i][21] = f2bf(an4); xsm[i][22] = f2bf(an5);
    }
    __syncthreads();  // B11
  }

  // ================= epilogue =================
  if (t < 192) { int r = t / 6, d = t - r * 6; out[abase + t] = tanhf(acur[r][d]); }
  if (t < 32) {
    float st = 0.f;
    #pragma unroll
    for (int d = 0; d < 6; ++d) {
      float x = acur[t][d];
      float z = -2.f * x;
      float sp = fmaxf(z, 0.f) + log1pf(expf(-fabsf(z)));
      st += 2.f * (0.69314718056f - x - sp);
    }
    float lpn = -3.0f * logf(1.88495559215f) - (0.5f / 0.3f) * asq[t];
    XSsh[t] = lpn + logps[t] - st;
  }
  __syncthreads();
  if (t == 0) {
    float s = 0.f;
    #pragma unroll
    for (int n = 0; n < 32; ++n) s += XSsh[n];
    out[196608 + b] = s * (1.0f / 32.0f);
  }
}

extern "C" void kernel_launch(void* const* d_in, const int* in_sizes, int n_in,
                              void* d_out, int out_size, void* d_ws, size_t ws_size,
                              hipStream_t stream) {
  const float* obs  = (const float*)d_in[0];
  const float* a0   = (const float*)d_in[1];
  const float* q1W1 = (const float*)d_in[2];
  const float* q1b1 = (const float*)d_in[3];
  const float* q1W2 = (const float*)d_in[4];
  const float* q1b2 = (const float*)d_in[5];
  const float* q1W3 = (const float*)d_in[6];
  const float* q1b3 = (const float*)d_in[7];
  const float* q2W1 = (const float*)d_in[8];
  const float* q2b1 = (const float*)d_in[9];
  const float* q2W2 = (const float*)d_in[10];
  const float* q2b2 = (const float*)d_in[11];
  const float* q2W3 = (const float*)d_in[12];
  const float* q2b3 = (const float*)d_in[13];

  unsigned short* wsu = (unsigned short*)d_ws;
  unsigned short* W2bfA  = wsu;
  unsigned short* W2bfB  = W2bfA + 65536;
  unsigned short* W2TbfA = W2bfB + 65536;
  unsigned short* W2TbfB = W2TbfA + 65536;
  unsigned short* W1TbfA = W2TbfB + 65536;
  unsigned short* W1TbfB = W1TbfA + 8192;
  unsigned short* W1tailA = W1TbfB + 8192;
  unsigned short* W1tailB = W1tailA + 4096;
  float* out  = (float*)d_out;

  prep_kernel<<<1120, 256, 0, stream>>>(q1W1, q2W1, q1W2, q2W2,
      W2bfA, W2bfB, W2TbfA, W2TbfB, W1TbfA, W1TbfB, W1tailA, W1tailB);

  fused_kernel<<<1024, 256, 0, stream>>>(obs, a0,
      q1b1, q1b2, q1W3, q1b3,
      q2b1, q2b2, q2W3, q2b3,
      W2bfA, W2bfB, W2TbfA, W2TbfB, W1TbfA, W1TbfB, W1tailA, W1tailB,
      out);
}

// Round 4
// 349.371 us; speedup vs baseline: 1.3226x; 1.1332x over previous
//
#include <hip/hip_runtime.h>
#include <math.h>

#define LR 0.05f

typedef __attribute__((ext_vector_type(8))) short short8;
typedef __attribute__((ext_vector_type(4))) float f32x4;

#define MFMA16(a, b, c) __builtin_amdgcn_mfma_f32_16x16x32_bf16(a, b, c, 0, 0, 0)

__device__ __forceinline__ unsigned short f2bf(float v) {
  unsigned int u = __float_as_uint(v);
  u += 0x7fffu + ((u >> 16) & 1u);
  return (unsigned short)(u >> 16);
}

__device__ __forceinline__ void ce2(float& a, float& b, bool asc) {
  float lo = fminf(a, b), hi = fmaxf(a, b);
  a = asc ? lo : hi; b = asc ? hi : lo;
}

// ---------------- prep: build FRAGMENT-ORDERED bf16 weight copies ------------
// All B-operand tiles stored so one wave-load = one contiguous 1KB block:
//   frag[tile*512 + l16*32 + quad*8 + e]  (tile = ct*K + k)
__global__ __launch_bounds__(256) void prep_kernel(
    const float* __restrict__ W1a, const float* __restrict__ W1b,
    const float* __restrict__ W2a, const float* __restrict__ W2b,
    unsigned short* __restrict__ W2bfA, unsigned short* __restrict__ W2bfB,
    unsigned short* __restrict__ W2TbfA, unsigned short* __restrict__ W2TbfB,
    unsigned short* __restrict__ W1TbfA, unsigned short* __restrict__ W1TbfB,
    unsigned short* __restrict__ W1tailA, unsigned short* __restrict__ W1tailB)
{
  int i = blockIdx.x * 256 + threadIdx.x;
  if (i < 131072) {
    const float* W2 = (i >> 16) ? W2b : W2a;
    unsigned short* o = (i >> 16) ? W2bfB : W2bfA;
    int j = i & 65535;
    int tile = j >> 9, within = j & 511;
    int l16 = within >> 5, rem = within & 31;
    int ct = tile >> 3, k = tile & 7;
    o[j] = f2bf(W2[(ct * 16 + l16) * 256 + k * 32 + rem]);
  } else if (i < 262144) {
    int i2 = i - 131072;
    const float* W2 = (i2 >> 16) ? W2b : W2a;
    unsigned short* o = (i2 >> 16) ? W2TbfB : W2TbfA;
    int j = i2 & 65535;
    int tile = j >> 9, within = j & 511;
    int l16 = within >> 5, rem = within & 31;
    int ct = tile >> 3, k = tile & 7;
    o[j] = f2bf(W2[(k * 32 + rem) * 256 + ct * 16 + l16]);
  } else if (i < 278528) {
    int i2 = i - 262144;
    const float* W1 = (i2 >> 13) ? W1b : W1a;
    unsigned short* o = (i2 >> 13) ? W1TbfB : W1TbfA;
    int j = i2 & 8191;
    int ct = j >> 9, within = j & 511;
    int l16 = within >> 5, rem = within & 31;
    o[j] = (rem < 23) ? f2bf(W1[rem * 256 + ct * 16 + l16]) : (unsigned short)0;
  } else if (i < 286720) {
    int i2 = i - 278528;
    const float* W1 = (i2 >> 12) ? W1b : W1a;
    unsigned short* o = (i2 >> 12) ? W1tailB : W1tailA;
    int j = i2 & 4095;
    int k = j >> 9, within = j & 511;
    int l16 = within >> 5, rem = within & 31;
    o[j] = (l16 < 6) ? f2bf(W1[(17 + l16) * 256 + k * 32 + rem]) : (unsigned short)0;
  }
}

// ---------------- fused: 5 x (score + SVGD) + epilogue, one block per batch --
// R3 post-mortem of R2 (333us): launch_bounds(256,4) tier doubled occupancy
// (22.6->45.6%) = the win; but merged accumulators spilled ~185MB to scratch
// (WRITE_SIZE 0.8MB->186MB), thrashing L2. R3: keep frag-ordered weights +
// the 4-waves/SIMD tier, revert to small accumulators (h2: two hf passes
// acc[2][2]; bwd: 4 single-col passes) so the frame fits 128 regs, no spill.
__global__ __launch_bounds__(256, 4) void fused_kernel(
    const float* __restrict__ obs, const float* __restrict__ a0,
    const float* __restrict__ b1a, const float* __restrict__ b2a,
    const float* __restrict__ W3a, const float* __restrict__ b3a,
    const float* __restrict__ b1b, const float* __restrict__ b2b,
    const float* __restrict__ W3b, const float* __restrict__ b3b,
    const unsigned short* __restrict__ W2bfA, const unsigned short* __restrict__ W2bfB,
    const unsigned short* __restrict__ W2TbfA, const unsigned short* __restrict__ W2TbfB,
    const unsigned short* __restrict__ W1TbfA, const unsigned short* __restrict__ W1TbfB,
    const unsigned short* __restrict__ W1tailA, const unsigned short* __restrict__ W1tailB,
    float* __restrict__ out)
{
  __shared__ __align__(16) unsigned short buf0[32][264];  // h1a -> dh2c; sortA/B alias
  __shared__ __align__(16) unsigned short buf1[32][264];  // h1b -> dh1_m
  __shared__ __align__(16) unsigned short xsm[32][40];    // bf16 x (obs cols persist)
  __shared__ __align__(16) float upool[384];              // qpart[2][4][32] | redS[64][6]
  __shared__ float acur[32][6];
  __shared__ float Svv[32][6];
  __shared__ float XSsh[32];
  __shared__ float logps[32];
  __shared__ float asq[32];
  __shared__ int   selsh[32];
  __shared__ float medsh[2];

  float (*qpart)[4][32] = (float (*)[4][32])upool;
  float (*redS)[6] = (float (*)[6])upool;

  const int t = threadIdx.x;
  const int lane = t & 63, wv = t >> 6, quad = lane >> 4, l16 = lane & 15;
  const int b = blockIdx.x;
  const int base = b * 32;
  const int ctb = wv * 4;
  const long abase = (long)b * 192;
  const int wfrag = l16 * 32 + quad * 8;   // lane's short-offset within a 1KB tile

  float* sortA = (float*)&buf0[0][0];   // 512 floats
  float* sortB = sortA + 512;           // 512 floats
  const int eb = t * 2;                 // this thread's 2 sort elements

  // triangular index map for sort elements 2t, 2t+1 (step-invariant, packed)
  int packij = 0;
  {
    #pragma unroll
    for (int m = 0; m < 2; ++m) {
      int e = eb + m;
      int ii = 0, jj = 0;
      if (e < 496) {
        float sq = sqrtf(992.25f - 2.0f * (float)e);
        ii = (int)(31.5f - sq);
        if (e >= ((ii + 1) * (62 - ii)) / 2) ++ii;
        else if (e < (ii * (63 - ii)) / 2) --ii;
        jj = ii + 1 + (e - (ii * (63 - ii)) / 2);
      }
      packij |= (ii | (jj << 5)) << (m * 10);
    }
  }

  // ---- init ----
  if (t < 192) { int r = t / 6, d = t - r * 6; acur[r][d] = a0[abase + t]; }
  if (t < 32) {
    float s = 0.f;
    #pragma unroll
    for (int d = 0; d < 6; ++d) { float x0 = a0[abase + t * 6 + d]; s += x0 * x0; }
    asq[t] = s; logps[t] = 0.f;
  }
  for (int idx = t; idx < 32 * 40; idx += 256) {
    int r = idx / 40, k = idx - r * 40;
    float v = 0.f;
    if (k < 17) v = obs[(base + r) * 17 + k];
    else if (k < 23) v = a0[abase + r * 6 + (k - 17)];
    xsm[r][k] = f2bf(v);
  }
  __syncthreads();

  #pragma unroll 1
  for (int s = 0; s < 5; ++s) {
    // ---- sort element values (regs) from acur ----
    float sv0 = 0.f, sv1 = 0.f;
    {
      int i0 = packij & 31, j0 = (packij >> 5) & 31;
      int i1 = (packij >> 10) & 31, j1 = (packij >> 15) & 31;
      #pragma unroll
      for (int d = 0; d < 6; ++d) {
        float d0 = acur[i0][d] - acur[j0][d]; sv0 += d0 * d0;
        float d1 = acur[i1][d] - acur[j1][d]; sv1 += d1 * d1;
      }
    }

    // ================= h1 both nets =================
    unsigned int m1a_bits = 0, m1b_bits = 0, m2a_bits = 0, m2b_bits = 0;
    #pragma unroll 1
    for (int net = 0; net < 2; ++net) {
      const unsigned short* W1T = net ? W1TbfB : W1TbfA;
      const float* b1 = net ? b1b : b1a;
      unsigned short (*hbuf)[264] = net ? buf1 : buf0;
      unsigned int m1 = 0;
      short8 ax0 = *(const short8*)&xsm[l16][quad * 8];
      short8 ax1 = *(const short8*)&xsm[16 + l16][quad * 8];
      #pragma unroll
      for (int c = 0; c < 4; ++c) {
        short8 bw = *(const short8*)&W1T[(ctb + c) * 512 + wfrag];
        int col = (ctb + c) * 16 + l16;
        f32x4 z = {0.f, 0.f, 0.f, 0.f};
        f32x4 h0 = MFMA16(ax0, bw, z);
        f32x4 h1v = MFMA16(ax1, bw, z);
        float b1v = b1[col];
        #pragma unroll
        for (int g = 0; g < 4; ++g) {
          float v0 = h0[g] + b1v;
          float v1 = h1v[g] + b1v;
          if (v0 > 0.f) m1 |= 1u << ((0 * 4 + c) * 4 + g);
          if (v1 > 0.f) m1 |= 1u << ((1 * 4 + c) * 4 + g);
          hbuf[quad * 4 + g][col] = (v0 > 0.f) ? f2bf(v0) : (unsigned short)0;
          hbuf[16 + quad * 4 + g][col] = (v1 > 0.f) ? f2bf(v1) : (unsigned short)0;
        }
      }
      if (net) m1b_bits = m1; else m1a_bits = m1;
    }
    __syncthreads();  // B1

    // ================= h2 both nets + qpart (two hf passes, acc[2][2]) ======
    #pragma unroll 1
    for (int net = 0; net < 2; ++net) {
      const unsigned short* W2T = net ? W2TbfB : W2TbfA;
      const float* b2 = net ? b2b : b2a;
      const float* W3 = net ? W3b : W3a;
      unsigned short (*hbuf)[264] = net ? buf1 : buf0;

      float pq[2][4] = {{0.f, 0.f, 0.f, 0.f}, {0.f, 0.f, 0.f, 0.f}};
      unsigned int m2 = 0;
      #pragma unroll 1
      for (int hf = 0; hf < 2; ++hf) {
        f32x4 acc[2][2];
        acc[0][0] = acc[0][1] = acc[1][0] = acc[1][1] = (f32x4){0.f, 0.f, 0.f, 0.f};
        #pragma unroll 2
        for (int k = 0; k < 8; ++k) {
          short8 a0f = *(const short8*)&hbuf[l16][k * 32 + quad * 8];
          short8 a1f = *(const short8*)&hbuf[16 + l16][k * 32 + quad * 8];
          #pragma unroll
          for (int c = 0; c < 2; ++c) {
            short8 bw = *(const short8*)&W2T[(ctb + hf * 2 + c) * 4096 + k * 512 + wfrag];
            acc[0][c] = MFMA16(a0f, bw, acc[0][c]);
            acc[1][c] = MFMA16(a1f, bw, acc[1][c]);
          }
        }
        #pragma unroll
        for (int rt = 0; rt < 2; ++rt)
          #pragma unroll
          for (int c = 0; c < 2; ++c) {
            int cc = hf * 2 + c;
            int col = (ctb + cc) * 16 + l16;
            float b2v = b2[col], w3v = W3[col];
            #pragma unroll
            for (int g = 0; g < 4; ++g) {
              float v = acc[rt][c][g] + b2v;
              if (v > 0.f) {
                m2 |= 1u << ((rt * 4 + cc) * 4 + g);
                pq[rt][g] += v * w3v;
              }
            }
          }
      }
      if (net) m2b_bits = m2; else m2a_bits = m2;
      #pragma unroll
      for (int off = 8; off; off >>= 1) {
        #pragma unroll
        for (int rt = 0; rt < 2; ++rt)
          #pragma unroll
          for (int g = 0; g < 4; ++g)
            pq[rt][g] += __shfl_xor(pq[rt][g], off, 16);
      }
      if (l16 == 0) {
        #pragma unroll
        for (int rt = 0; rt < 2; ++rt)
          #pragma unroll
          for (int g = 0; g < 4; ++g)
            qpart[net][wv][rt * 16 + quad * 4 + g] = pq[rt][g];
      }
    }
    __syncthreads();  // B2

    // ---- sel (t<32) + intra-wave sort k=2..128 (barrier bubble filler) ----
    if (t < 32) {
      float qa = b3a[0], qb = b3b[0];
      #pragma unroll
      for (int w = 0; w < 4; ++w) { qa += qpart[0][w][t]; qb += qpart[1][w][t]; }
      selsh[t] = (qa <= qb) ? 0 : 1;
    }
    #pragma unroll
    for (int k = 2; k <= 128; k <<= 1) {
      #pragma unroll
      for (int j = k >> 1; j >= 2; j >>= 1) {
        int lm = j >> 1;
        bool km = (((eb & j) == 0) == ((eb & k) == 0));
        float p0 = __shfl_xor(sv0, lm);
        sv0 = km ? fminf(sv0, p0) : fmaxf(sv0, p0);
        float p1 = __shfl_xor(sv1, lm);
        sv1 = km ? fminf(sv1, p1) : fmaxf(sv1, p1);
      }
      ce2(sv0, sv1, ((eb & k) == 0));
    }
    __syncthreads();  // B3

    // ---- dh2c: single buffer, selected net only ----
    #pragma unroll
    for (int rt = 0; rt < 2; ++rt)
      #pragma unroll
      for (int c = 0; c < 4; ++c) {
        int col = (ctb + c) * 16 + l16;
        unsigned short w3abf = f2bf(W3a[col]);
        unsigned short w3bbf = f2bf(W3b[col]);
        #pragma unroll
        for (int g = 0; g < 4; ++g) {
          int row = rt * 16 + quad * 4 + g;
          int sl = selsh[row];
          int bit = (rt * 4 + c) * 4 + g;
          unsigned int mb = sl ? m2b_bits : m2a_bits;
          unsigned short wv3 = sl ? w3bbf : w3abf;
          buf0[row][col] = ((mb >> bit) & 1) ? wv3 : (unsigned short)0;
        }
      }
    __syncthreads();  // B4

    // ---- bwd: 4 one-col-tile passes; masked dh1 -> buf1 ----
    #pragma unroll 1
    for (int p = 0; p < 4; ++p) {
      f32x4 ba[2], bb[2];
      ba[0] = ba[1] = bb[0] = bb[1] = (f32x4){0.f, 0.f, 0.f, 0.f};
      #pragma unroll 2
      for (int k = 0; k < 8; ++k) {
        short8 bwA = *(const short8*)&W2bfA[(ctb + p) * 4096 + k * 512 + wfrag];
        short8 bwB = *(const short8*)&W2bfB[(ctb + p) * 4096 + k * 512 + wfrag];
        short8 a0d = *(const short8*)&buf0[l16][k * 32 + quad * 8];
        short8 a1d = *(const short8*)&buf0[16 + l16][k * 32 + quad * 8];
        ba[0] = MFMA16(a0d, bwA, ba[0]);
        bb[0] = MFMA16(a0d, bwB, bb[0]);
        ba[1] = MFMA16(a1d, bwA, ba[1]);
        bb[1] = MFMA16(a1d, bwB, bb[1]);
      }
      int col = (ctb + p) * 16 + l16;
      #pragma unroll
      for (int rt = 0; rt < 2; ++rt)
        #pragma unroll
        for (int g = 0; g < 4; ++g) {
          int row = rt * 16 + quad * 4 + g;
          int sl = selsh[row];
          float val = sl ? bb[rt][g] : ba[rt][g];
          unsigned int mb = sl ? m1b_bits : m1a_bits;
          int bit = (rt * 4 + p) * 4 + g;
          buf1[row][col] = ((mb >> bit) & 1) ? f2bf(val) : (unsigned short)0;
        }
    }
    __syncthreads();  // B5

    // ---- S (both nets from dh1) + sort stage1 write (buf0 now dead) ----
    {
      int net = wv >> 1, rt = wv & 1;
      const unsigned short* Wt = net ? W1tailB : W1tailA;
      f32x4 sacc = {0.f, 0.f, 0.f, 0.f};
      #pragma unroll 2
      for (int k = 0; k < 8; ++k) {
        short8 a = *(const short8*)&buf1[rt * 16 + l16][k * 32 + quad * 8];
        short8 bb2 = *(const short8*)&Wt[k * 512 + wfrag];
        sacc = MFMA16(a, bb2, sacc);
      }
      if (l16 < 6) {
        #pragma unroll
        for (int g = 0; g < 4; ++g)
          redS[net * 32 + rt * 16 + quad * 4 + g][l16] = sacc[g];
      }
    }
    sortA[eb] = sv0; sortA[eb + 1] = sv1;
    __syncthreads();  // B6

    // ---- sort stage1 read (k=256, j=128) + tail + Svv fill + stage2 write --
    {
      bool km = (((eb & 128) == 0) == ((eb & 256) == 0));
      float p0 = sortA[eb ^ 128];
      float p1 = sortA[(eb ^ 128) + 1];
      sv0 = km ? fminf(sv0, p0) : fmaxf(sv0, p0);
      sv1 = km ? fminf(sv1, p1) : fmaxf(sv1, p1);
      #pragma unroll
      for (int j = 64; j >= 2; j >>= 1) {
        int lm = j >> 1;
        bool k2 = (((eb & j) == 0) == ((eb & 256) == 0));
        float q0 = __shfl_xor(sv0, lm);
        sv0 = k2 ? fminf(sv0, q0) : fmaxf(sv0, q0);
        float q1 = __shfl_xor(sv1, lm);
        sv1 = k2 ? fminf(sv1, q1) : fmaxf(sv1, q1);
      }
      ce2(sv0, sv1, ((eb & 256) == 0));
    }
    if (t < 192) { int r = t / 6, d = t - r * 6; Svv[r][d] = redS[selsh[r] * 32 + r][d]; }
    sortB[eb] = sv0; sortB[eb + 1] = sv1;
    __syncthreads();  // B7

    // ---- sort stage2 read (k=512, j=256) + XSsh + stage3 write ----
    {
      bool km = ((eb & 256) == 0);
      float p0 = sortB[eb ^ 256];
      float p1 = sortB[(eb ^ 256) + 1];
      sv0 = km ? fminf(sv0, p0) : fmaxf(sv0, p0);
      sv1 = km ? fminf(sv1, p1) : fmaxf(sv1, p1);
    }
    if (t < 32) {
      float sx = 0.f;
      #pragma unroll
      for (int d = 0; d < 6; ++d) sx += acur[t][d] * Svv[t][d];
      XSsh[t] = sx;
    }
    sortA[eb] = sv0; sortA[eb + 1] = sv1;
    __syncthreads();  // B8

    // ---- sort stage3 read (j=128) + final tail + median ----
    {
      bool km = ((eb & 128) == 0);
      float p0 = sortA[eb ^ 128];
      float p1 = sortA[(eb ^ 128) + 1];
      sv0 = km ? fminf(sv0, p0) : fmaxf(sv0, p0);
      sv1 = km ? fminf(sv1, p1) : fmaxf(sv1, p1);
      #pragma unroll
      for (int j = 64; j >= 2; j >>= 1) {
        int lm = j >> 1;
        bool k2 = ((eb & j) == 0);
        float q0 = __shfl_xor(sv0, lm);
        sv0 = k2 ? fminf(sv0, q0) : fmaxf(sv0, q0);
        float q1 = __shfl_xor(sv1, lm);
        sv1 = k2 ? fminf(sv1, q1) : fmaxf(sv1, q1);
      }
      ce2(sv0, sv1, true);
    }
    if (t == 127) medsh[0] = sv1;  // element 255
    if (t == 128) medsh[1] = sv0;  // element 256
    __syncthreads();  // B9

    // ================= K row-sums + update (dv recomputed from acur) ========
    float med = 0.5f * (medsh[0] + medsh[1]);
    float g = 1.0f / (2.0f * (med / logf(33.0f)) + 1e-8f);

    const int i = t >> 3, l = t & 7;
    float ai0 = acur[i][0], ai1 = acur[i][1], ai2 = acur[i][2];
    float ai3 = acur[i][3], ai4 = acur[i][4], ai5 = acur[i][5];
    float ks0=0,ks1=0,ks2=0,ks3=0,ks4=0,ks5=0;
    float kx0=0,kx1=0,kx2=0,kx3=0,kx4=0,kx5=0;
    float krow=0.f, kd2=0.f, kxs=0.f;
    #pragma unroll
    for (int jj = 0; jj < 4; ++jj) {
      int j = l + 8 * jj;
      float aj0 = acur[j][0], aj1 = acur[j][1], aj2 = acur[j][2];
      float aj3 = acur[j][3], aj4 = acur[j][4], aj5 = acur[j][5];
      float dv = 0.f, df;
      df = ai0 - aj0; dv += df * df;
      df = ai1 - aj1; dv += df * df;
      df = ai2 - aj2; dv += df * df;
      df = ai3 - aj3; dv += df * df;
      df = ai4 - aj4; dv += df * df;
      df = ai5 - aj5; dv += df * df;
      float kv = expf(-g * dv);
      krow += kv; kd2 += kv * dv; kxs += kv * XSsh[j];
      ks0 += kv * Svv[j][0]; kx0 += kv * aj0;
      ks1 += kv * Svv[j][1]; kx1 += kv * aj1;
      ks2 += kv * Svv[j][2]; kx2 += kv * aj2;
      ks3 += kv * Svv[j][3]; kx3 += kv * aj3;
      ks4 += kv * Svv[j][4]; kx4 += kv * aj4;
      ks5 += kv * Svv[j][5]; kx5 += kv * aj5;
    }
    #pragma unroll
    for (int off = 4; off > 0; off >>= 1) {
      krow += __shfl_down(krow, off, 8);
      kd2  += __shfl_down(kd2,  off, 8);
      kxs  += __shfl_down(kxs,  off, 8);
      ks0 += __shfl_down(ks0, off, 8); kx0 += __shfl_down(kx0, off, 8);
      ks1 += __shfl_down(ks1, off, 8); kx1 += __shfl_down(kx1, off, 8);
      ks2 += __shfl_down(ks2, off, 8); kx2 += __shfl_down(kx2, off, 8);
      ks3 += __shfl_down(ks3, off, 8); kx3 += __shfl_down(kx3, off, 8);
      ks4 += __shfl_down(ks4, off, 8); kx4 += __shfl_down(kx4, off, 8);
      ks5 += __shfl_down(ks5, off, 8); kx5 += __shfl_down(kx5, off, 8);
    }
    float an0=0,an1=0,an2=0,an3=0,an4=0,an5=0, lpnew=0;
    if (l == 0) {
      const float inv_n = 1.0f / 32.0f;
      float t1sum = 0.f, p;
      p = (ks0 + 2.f*g*(ai0*krow - kx0)) * inv_n; an0 = ai0 + LR * p; t1sum += ai0 * ks0;
      p = (ks1 + 2.f*g*(ai1*krow - kx1)) * inv_n; an1 = ai1 + LR * p; t1sum += ai1 * ks1;
      p = (ks2 + 2.f*g*(ai2*krow - kx2)) * inv_n; an2 = ai2 + LR * p; t1sum += ai2 * ks2;
      p = (ks3 + 2.f*g*(ai3*krow - kx3)) * inv_n; an3 = ai3 + LR * p; t1sum += ai3 * ks3;
      p = (ks4 + 2.f*g*(ai4*krow - kx4)) * inv_n; an4 = ai4 + LR * p; t1sum += ai4 * ks4;
      p = (ks5 + 2.f*g*(ai5*krow - kx5)) * inv_n; an5 = ai5 + LR * p; t1sum += ai5 * ks5;
      float term1 = (-2.f * g / 31.f) * (t1sum - kxs);
      float term2 = (-2.f * g / 31.f) * (2.f * g * kd2 - 6.f * (krow - 1.f));
      lpnew = logps[i] - LR * (term1 + term2);
    }
    __syncthreads();  // B10
    if (l == 0) {
      acur[i][0] = an0; acur[i][1] = an1; acur[i][2] = an2;
      acur[i][3] = an3; acur[i][4] = an4; acur[i][5] = an5;
      logps[i] = lpnew;
      xsm[i][17] = f2bf(an0); xsm[i][18] = f2bf(an1); xsm[i][19] = f2bf(an2);
      xsm[i][20] = f2bf(an3); xsm[i][21] = f2bf(an4); xsm[i][22] = f2bf(an5);
    }
    __syncthreads();  // B11
  }

  // ================= epilogue =================
  if (t < 192) { int r = t / 6, d = t - r * 6; out[abase + t] = tanhf(acur[r][d]); }
  if (t < 32) {
    float st = 0.f;
    #pragma unroll
    for (int d = 0; d < 6; ++d) {
      float x = acur[t][d];
      float z = -2.f * x;
      float sp = fmaxf(z, 0.f) + log1pf(expf(-fabsf(z)));
      st += 2.f * (0.69314718056f - x - sp);
    }
    float lpn = -3.0f * logf(1.88495559215f) - (0.5f / 0.3f) * asq[t];
    XSsh[t] = lpn + logps[t] - st;
  }
  __syncthreads();
  if (t == 0) {
    float s = 0.f;
    #pragma unroll
    for (int n = 0; n < 32; ++n) s += XSsh[n];
    out[196608 + b] = s * (1.0f / 32.0f);
  }
}

extern "C" void kernel_launch(void* const* d_in, const int* in_sizes, int n_in,
                              void* d_out, int out_size, void* d_ws, size_t ws_size,
                              hipStream_t stream) {
  const float* obs  = (const float*)d_in[0];
  const float* a0   = (const float*)d_in[1];
  const float* q1W1 = (const float*)d_in[2];
  const float* q1b1 = (const float*)d_in[3];
  const float* q1W2 = (const float*)d_in[4];
  const float* q1b2 = (const float*)d_in[5];
  const float* q1W3 = (const float*)d_in[6];
  const float* q1b3 = (const float*)d_in[7];
  const float* q2W1 = (const float*)d_in[8];
  const float* q2b1 = (const float*)d_in[9];
  const float* q2W2 = (const float*)d_in[10];
  const float* q2b2 = (const float*)d_in[11];
  const float* q2W3 = (const float*)d_in[12];
  const float* q2b3 = (const float*)d_in[13];

  unsigned short* wsu = (unsigned short*)d_ws;
  unsigned short* W2bfA  = wsu;
  unsigned short* W2bfB  = W2bfA + 65536;
  unsigned short* W2TbfA = W2bfB + 65536;
  unsigned short* W2TbfB = W2TbfA + 65536;
  unsigned short* W1TbfA = W2TbfB + 65536;
  unsigned short* W1TbfB = W1TbfA + 8192;
  unsigned short* W1tailA = W1TbfB + 8192;
  unsigned short* W1tailB = W1tailA + 4096;
  float* out  = (float*)d_out;

  prep_kernel<<<1120, 256, 0, stream>>>(q1W1, q2W1, q1W2, q2W2,
      W2bfA, W2bfB, W2TbfA, W2TbfB, W1TbfA, W1TbfB, W1tailA, W1tailB);

  fused_kernel<<<1024, 256, 0, stream>>>(obs, a0,
      q1b1, q1b2, q1W3, q1b3,
      q2b1, q2b2, q2W3, q2b3,
      W2bfA, W2bfB, W2TbfA, W2TbfB, W1TbfA, W1TbfB, W1tailA, W1tailB,
      out);
}

// Round 5
// 322.472 us; speedup vs baseline: 1.4329x; 1.0834x over previous
//
#include <hip/hip_runtime.h>
#include <math.h>

#define LR 0.05f

typedef __attribute__((ext_vector_type(8))) short short8;
typedef __attribute__((ext_vector_type(4))) float f32x4;

#define MFMA16(a, b, c) __builtin_amdgcn_mfma_f32_16x16x32_bf16(a, b, c, 0, 0, 0)

__device__ __forceinline__ unsigned short f2bf(float v) {
  unsigned int u = __float_as_uint(v);
  u += 0x7fffu + ((u >> 16) & 1u);
  return (unsigned short)(u >> 16);
}

__device__ __forceinline__ void ce2(float& a, float& b, bool asc) {
  float lo = fminf(a, b), hi = fmaxf(a, b);
  a = asc ? lo : hi; b = asc ? hi : lo;
}

// ---------------- prep: build FRAGMENT-ORDERED bf16 weight copies ------------
// All B-operand tiles stored so one wave-load = one contiguous 1KB block:
//   frag[tile*512 + l16*32 + quad*8 + e]  (tile = ct*K + k)
__global__ __launch_bounds__(256) void prep_kernel(
    const float* __restrict__ W1a, const float* __restrict__ W1b,
    const float* __restrict__ W2a, const float* __restrict__ W2b,
    unsigned short* __restrict__ W2bfA, unsigned short* __restrict__ W2bfB,
    unsigned short* __restrict__ W2TbfA, unsigned short* __restrict__ W2TbfB,
    unsigned short* __restrict__ W1TbfA, unsigned short* __restrict__ W1TbfB,
    unsigned short* __restrict__ W1tailA, unsigned short* __restrict__ W1tailB)
{
  int i = blockIdx.x * 256 + threadIdx.x;
  if (i < 131072) {
    const float* W2 = (i >> 16) ? W2b : W2a;
    unsigned short* o = (i >> 16) ? W2bfB : W2bfA;
    int j = i & 65535;
    int tile = j >> 9, within = j & 511;
    int l16 = within >> 5, rem = within & 31;
    int ct = tile >> 3, k = tile & 7;
    o[j] = f2bf(W2[(ct * 16 + l16) * 256 + k * 32 + rem]);
  } else if (i < 262144) {
    int i2 = i - 131072;
    const float* W2 = (i2 >> 16) ? W2b : W2a;
    unsigned short* o = (i2 >> 16) ? W2TbfB : W2TbfA;
    int j = i2 & 65535;
    int tile = j >> 9, within = j & 511;
    int l16 = within >> 5, rem = within & 31;
    int ct = tile >> 3, k = tile & 7;
    o[j] = f2bf(W2[(k * 32 + rem) * 256 + ct * 16 + l16]);
  } else if (i < 278528) {
    int i2 = i - 262144;
    const float* W1 = (i2 >> 13) ? W1b : W1a;
    unsigned short* o = (i2 >> 13) ? W1TbfB : W1TbfA;
    int j = i2 & 8191;
    int ct = j >> 9, within = j & 511;
    int l16 = within >> 5, rem = within & 31;
    o[j] = (rem < 23) ? f2bf(W1[rem * 256 + ct * 16 + l16]) : (unsigned short)0;
  } else if (i < 286720) {
    int i2 = i - 278528;
    const float* W1 = (i2 >> 12) ? W1b : W1a;
    unsigned short* o = (i2 >> 12) ? W1tailB : W1tailA;
    int j = i2 & 4095;
    int k = j >> 9, within = j & 511;
    int l16 = within >> 5, rem = within & 31;
    o[j] = (l16 < 6) ? f2bf(W1[(17 + l16) * 256 + k * 32 + rem]) : (unsigned short)0;
  }
}

// ---------------- fused: 5 x (score + SVGD) + epilogue, one block per batch --
// R4: R3 still spilled 93MB (WRITE_SIZE) despite 16-reg accumulators -> theory:
// scheduler hoists k-loop weight loads (unroll 2 x independent dwordx4) past
// the 128-reg budget. Fix: #pragma unroll 1 on h2/bwd/S k-loops to cap the
// in-flight load window; 16 waves/CU TLP hides per-iter L2 latency.
// Math order unchanged -> bit-identical.
__global__ __launch_bounds__(256, 4) void fused_kernel(
    const float* __restrict__ obs, const float* __restrict__ a0,
    const float* __restrict__ b1a, const float* __restrict__ b2a,
    const float* __restrict__ W3a, const float* __restrict__ b3a,
    const float* __restrict__ b1b, const float* __restrict__ b2b,
    const float* __restrict__ W3b, const float* __restrict__ b3b,
    const unsigned short* __restrict__ W2bfA, const unsigned short* __restrict__ W2bfB,
    const unsigned short* __restrict__ W2TbfA, const unsigned short* __restrict__ W2TbfB,
    const unsigned short* __restrict__ W1TbfA, const unsigned short* __restrict__ W1TbfB,
    const unsigned short* __restrict__ W1tailA, const unsigned short* __restrict__ W1tailB,
    float* __restrict__ out)
{
  __shared__ __align__(16) unsigned short buf0[32][264];  // h1a -> dh2c; sortA/B alias
  __shared__ __align__(16) unsigned short buf1[32][264];  // h1b -> dh1_m
  __shared__ __align__(16) unsigned short xsm[32][40];    // bf16 x (obs cols persist)
  __shared__ __align__(16) float upool[384];              // qpart[2][4][32] | redS[64][6]
  __shared__ float acur[32][6];
  __shared__ float Svv[32][6];
  __shared__ float XSsh[32];
  __shared__ float logps[32];
  __shared__ float asq[32];
  __shared__ int   selsh[32];
  __shared__ float medsh[2];

  float (*qpart)[4][32] = (float (*)[4][32])upool;
  float (*redS)[6] = (float (*)[6])upool;

  const int t = threadIdx.x;
  const int lane = t & 63, wv = t >> 6, quad = lane >> 4, l16 = lane & 15;
  const int b = blockIdx.x;
  const int base = b * 32;
  const int ctb = wv * 4;
  const long abase = (long)b * 192;
  const int wfrag = l16 * 32 + quad * 8;   // lane's short-offset within a 1KB tile

  float* sortA = (float*)&buf0[0][0];   // 512 floats
  float* sortB = sortA + 512;           // 512 floats
  const int eb = t * 2;                 // this thread's 2 sort elements

  // triangular index map for sort elements 2t, 2t+1 (step-invariant, packed)
  int packij = 0;
  {
    #pragma unroll
    for (int m = 0; m < 2; ++m) {
      int e = eb + m;
      int ii = 0, jj = 0;
      if (e < 496) {
        float sq = sqrtf(992.25f - 2.0f * (float)e);
        ii = (int)(31.5f - sq);
        if (e >= ((ii + 1) * (62 - ii)) / 2) ++ii;
        else if (e < (ii * (63 - ii)) / 2) --ii;
        jj = ii + 1 + (e - (ii * (63 - ii)) / 2);
      }
      packij |= (ii | (jj << 5)) << (m * 10);
    }
  }

  // ---- init ----
  if (t < 192) { int r = t / 6, d = t - r * 6; acur[r][d] = a0[abase + t]; }
  if (t < 32) {
    float s = 0.f;
    #pragma unroll
    for (int d = 0; d < 6; ++d) { float x0 = a0[abase + t * 6 + d]; s += x0 * x0; }
    asq[t] = s; logps[t] = 0.f;
  }
  for (int idx = t; idx < 32 * 40; idx += 256) {
    int r = idx / 40, k = idx - r * 40;
    float v = 0.f;
    if (k < 17) v = obs[(base + r) * 17 + k];
    else if (k < 23) v = a0[abase + r * 6 + (k - 17)];
    xsm[r][k] = f2bf(v);
  }
  __syncthreads();

  #pragma unroll 1
  for (int s = 0; s < 5; ++s) {
    // ---- sort element values (regs) from acur ----
    float sv0 = 0.f, sv1 = 0.f;
    {
      int i0 = packij & 31, j0 = (packij >> 5) & 31;
      int i1 = (packij >> 10) & 31, j1 = (packij >> 15) & 31;
      #pragma unroll
      for (int d = 0; d < 6; ++d) {
        float d0 = acur[i0][d] - acur[j0][d]; sv0 += d0 * d0;
        float d1 = acur[i1][d] - acur[j1][d]; sv1 += d1 * d1;
      }
    }

    // ================= h1 both nets =================
    unsigned int m1a_bits = 0, m1b_bits = 0, m2a_bits = 0, m2b_bits = 0;
    #pragma unroll 1
    for (int net = 0; net < 2; ++net) {
      const unsigned short* W1T = net ? W1TbfB : W1TbfA;
      const float* b1 = net ? b1b : b1a;
      unsigned short (*hbuf)[264] = net ? buf1 : buf0;
      unsigned int m1 = 0;
      short8 ax0 = *(const short8*)&xsm[l16][quad * 8];
      short8 ax1 = *(const short8*)&xsm[16 + l16][quad * 8];
      #pragma unroll
      for (int c = 0; c < 4; ++c) {
        short8 bw = *(const short8*)&W1T[(ctb + c) * 512 + wfrag];
        int col = (ctb + c) * 16 + l16;
        f32x4 z = {0.f, 0.f, 0.f, 0.f};
        f32x4 h0 = MFMA16(ax0, bw, z);
        f32x4 h1v = MFMA16(ax1, bw, z);
        float b1v = b1[col];
        #pragma unroll
        for (int g = 0; g < 4; ++g) {
          float v0 = h0[g] + b1v;
          float v1 = h1v[g] + b1v;
          if (v0 > 0.f) m1 |= 1u << ((0 * 4 + c) * 4 + g);
          if (v1 > 0.f) m1 |= 1u << ((1 * 4 + c) * 4 + g);
          hbuf[quad * 4 + g][col] = (v0 > 0.f) ? f2bf(v0) : (unsigned short)0;
          hbuf[16 + quad * 4 + g][col] = (v1 > 0.f) ? f2bf(v1) : (unsigned short)0;
        }
      }
      if (net) m1b_bits = m1; else m1a_bits = m1;
    }
    __syncthreads();  // B1

    // ================= h2 both nets + qpart (two hf passes, acc[2][2]) ======
    #pragma unroll 1
    for (int net = 0; net < 2; ++net) {
      const unsigned short* W2T = net ? W2TbfB : W2TbfA;
      const float* b2 = net ? b2b : b2a;
      const float* W3 = net ? W3b : W3a;
      unsigned short (*hbuf)[264] = net ? buf1 : buf0;

      float pq[2][4] = {{0.f, 0.f, 0.f, 0.f}, {0.f, 0.f, 0.f, 0.f}};
      unsigned int m2 = 0;
      #pragma unroll 1
      for (int hf = 0; hf < 2; ++hf) {
        f32x4 acc[2][2];
        acc[0][0] = acc[0][1] = acc[1][0] = acc[1][1] = (f32x4){0.f, 0.f, 0.f, 0.f};
        #pragma unroll 1
        for (int k = 0; k < 8; ++k) {
          short8 a0f = *(const short8*)&hbuf[l16][k * 32 + quad * 8];
          short8 a1f = *(const short8*)&hbuf[16 + l16][k * 32 + quad * 8];
          #pragma unroll
          for (int c = 0; c < 2; ++c) {
            short8 bw = *(const short8*)&W2T[(ctb + hf * 2 + c) * 4096 + k * 512 + wfrag];
            acc[0][c] = MFMA16(a0f, bw, acc[0][c]);
            acc[1][c] = MFMA16(a1f, bw, acc[1][c]);
          }
        }
        #pragma unroll
        for (int rt = 0; rt < 2; ++rt)
          #pragma unroll
          for (int c = 0; c < 2; ++c) {
            int cc = hf * 2 + c;
            int col = (ctb + cc) * 16 + l16;
            float b2v = b2[col], w3v = W3[col];
            #pragma unroll
            for (int g = 0; g < 4; ++g) {
              float v = acc[rt][c][g] + b2v;
              if (v > 0.f) {
                m2 |= 1u << ((rt * 4 + cc) * 4 + g);
                pq[rt][g] += v * w3v;
              }
            }
          }
      }
      if (net) m2b_bits = m2; else m2a_bits = m2;
      #pragma unroll
      for (int off = 8; off; off >>= 1) {
        #pragma unroll
        for (int rt = 0; rt < 2; ++rt)
          #pragma unroll
          for (int g = 0; g < 4; ++g)
            pq[rt][g] += __shfl_xor(pq[rt][g], off, 16);
      }
      if (l16 == 0) {
        #pragma unroll
        for (int rt = 0; rt < 2; ++rt)
          #pragma unroll
          for (int g = 0; g < 4; ++g)
            qpart[net][wv][rt * 16 + quad * 4 + g] = pq[rt][g];
      }
    }
    __syncthreads();  // B2

    // ---- sel (t<32) + intra-wave sort k=2..128 (barrier bubble filler) ----
    if (t < 32) {
      float qa = b3a[0], qb = b3b[0];
      #pragma unroll
      for (int w = 0; w < 4; ++w) { qa += qpart[0][w][t]; qb += qpart[1][w][t]; }
      selsh[t] = (qa <= qb) ? 0 : 1;
    }
    #pragma unroll
    for (int k = 2; k <= 128; k <<= 1) {
      #pragma unroll
      for (int j = k >> 1; j >= 2; j >>= 1) {
        int lm = j >> 1;
        bool km = (((eb & j) == 0) == ((eb & k) == 0));
        float p0 = __shfl_xor(sv0, lm);
        sv0 = km ? fminf(sv0, p0) : fmaxf(sv0, p0);
        float p1 = __shfl_xor(sv1, lm);
        sv1 = km ? fminf(sv1, p1) : fmaxf(sv1, p1);
      }
      ce2(sv0, sv1, ((eb & k) == 0));
    }
    __syncthreads();  // B3

    // ---- dh2c: single buffer, selected net only ----
    #pragma unroll
    for (int rt = 0; rt < 2; ++rt)
      #pragma unroll
      for (int c = 0; c < 4; ++c) {
        int col = (ctb + c) * 16 + l16;
        unsigned short w3abf = f2bf(W3a[col]);
        unsigned short w3bbf = f2bf(W3b[col]);
        #pragma unroll
        for (int g = 0; g < 4; ++g) {
          int row = rt * 16 + quad * 4 + g;
          int sl = selsh[row];
          int bit = (rt * 4 + c) * 4 + g;
          unsigned int mb = sl ? m2b_bits : m2a_bits;
          unsigned short wv3 = sl ? w3bbf : w3abf;
          buf0[row][col] = ((mb >> bit) & 1) ? wv3 : (unsigned short)0;
        }
      }
    __syncthreads();  // B4

    // ---- bwd: 4 one-col-tile passes; masked dh1 -> buf1 ----
    #pragma unroll 1
    for (int p = 0; p < 4; ++p) {
      f32x4 ba[2], bb[2];
      ba[0] = ba[1] = bb[0] = bb[1] = (f32x4){0.f, 0.f, 0.f, 0.f};
      #pragma unroll 1
      for (int k = 0; k < 8; ++k) {
        short8 bwA = *(const short8*)&W2bfA[(ctb + p) * 4096 + k * 512 + wfrag];
        short8 bwB = *(const short8*)&W2bfB[(ctb + p) * 4096 + k * 512 + wfrag];
        short8 a0d = *(const short8*)&buf0[l16][k * 32 + quad * 8];
        short8 a1d = *(const short8*)&buf0[16 + l16][k * 32 + quad * 8];
        ba[0] = MFMA16(a0d, bwA, ba[0]);
        bb[0] = MFMA16(a0d, bwB, bb[0]);
        ba[1] = MFMA16(a1d, bwA, ba[1]);
        bb[1] = MFMA16(a1d, bwB, bb[1]);
      }
      int col = (ctb + p) * 16 + l16;
      #pragma unroll
      for (int rt = 0; rt < 2; ++rt)
        #pragma unroll
        for (int g = 0; g < 4; ++g) {
          int row = rt * 16 + quad * 4 + g;
          int sl = selsh[row];
          float val = sl ? bb[rt][g] : ba[rt][g];
          unsigned int mb = sl ? m1b_bits : m1a_bits;
          int bit = (rt * 4 + p) * 4 + g;
          buf1[row][col] = ((mb >> bit) & 1) ? f2bf(val) : (unsigned short)0;
        }
    }
    __syncthreads();  // B5

    // ---- S (both nets from dh1) + sort stage1 write (buf0 now dead) ----
    {
      int net = wv >> 1, rt = wv & 1;
      const unsigned short* Wt = net ? W1tailB : W1tailA;
      f32x4 sacc = {0.f, 0.f, 0.f, 0.f};
      #pragma unroll 1
      for (int k = 0; k < 8; ++k) {
        short8 a = *(const short8*)&buf1[rt * 16 + l16][k * 32 + quad * 8];
        short8 bb2 = *(const short8*)&Wt[k * 512 + wfrag];
        sacc = MFMA16(a, bb2, sacc);
      }
      if (l16 < 6) {
        #pragma unroll
        for (int g = 0; g < 4; ++g)
          redS[net * 32 + rt * 16 + quad * 4 + g][l16] = sacc[g];
      }
    }
    sortA[eb] = sv0; sortA[eb + 1] = sv1;
    __syncthreads();  // B6

    // ---- sort stage1 read (k=256, j=128) + tail + Svv fill + stage2 write --
    {
      bool km = (((eb & 128) == 0) == ((eb & 256) == 0));
      float p0 = sortA[eb ^ 128];
      float p1 = sortA[(eb ^ 128) + 1];
      sv0 = km ? fminf(sv0, p0) : fmaxf(sv0, p0);
      sv1 = km ? fminf(sv1, p1) : fmaxf(sv1, p1);
      #pragma unroll
      for (int j = 64; j >= 2; j >>= 1) {
        int lm = j >> 1;
        bool k2 = (((eb & j) == 0) == ((eb & 256) == 0));
        float q0 = __shfl_xor(sv0, lm);
        sv0 = k2 ? fminf(sv0, q0) : fmaxf(sv0, q0);
        float q1 = __shfl_xor(sv1, lm);
        sv1 = k2 ? fminf(sv1, q1) : fmaxf(sv1, q1);
      }
      ce2(sv0, sv1, ((eb & 256) == 0));
    }
    if (t < 192) { int r = t / 6, d = t - r * 6; Svv[r][d] = redS[selsh[r] * 32 + r][d]; }
    sortB[eb] = sv0; sortB[eb + 1] = sv1;
    __syncthreads();  // B7

    // ---- sort stage2 read (k=512, j=256) + XSsh + stage3 write ----
    {
      bool km = ((eb & 256) == 0);
      float p0 = sortB[eb ^ 256];
      float p1 = sortB[(eb ^ 256) + 1];
      sv0 = km ? fminf(sv0, p0) : fmaxf(sv0, p0);
      sv1 = km ? fminf(sv1, p1) : fmaxf(sv1, p1);
    }
    if (t < 32) {
      float sx = 0.f;
      #pragma unroll
      for (int d = 0; d < 6; ++d) sx += acur[t][d] * Svv[t][d];
      XSsh[t] = sx;
    }
    sortA[eb] = sv0; sortA[eb + 1] = sv1;
    __syncthreads();  // B8

    // ---- sort stage3 read (j=128) + final tail + median ----
    {
      bool km = ((eb & 128) == 0);
      float p0 = sortA[eb ^ 128];
      float p1 = sortA[(eb ^ 128) + 1];
      sv0 = km ? fminf(sv0, p0) : fmaxf(sv0, p0);
      sv1 = km ? fminf(sv1, p1) : fmaxf(sv1, p1);
      #pragma unroll
      for (int j = 64; j >= 2; j >>= 1) {
        int lm = j >> 1;
        bool k2 = ((eb & j) == 0);
        float q0 = __shfl_xor(sv0, lm);
        sv0 = k2 ? fminf(sv0, q0) : fmaxf(sv0, q0);
        float q1 = __shfl_xor(sv1, lm);
        sv1 = k2 ? fminf(sv1, q1) : fmaxf(sv1, q1);
      }
      ce2(sv0, sv1, true);
    }
    if (t == 127) medsh[0] = sv1;  // element 255
    if (t == 128) medsh[1] = sv0;  // element 256
    __syncthreads();  // B9

    // ================= K row-sums + update (dv recomputed from acur) ========
    float med = 0.5f * (medsh[0] + medsh[1]);
    float g = 1.0f / (2.0f * (med / logf(33.0f)) + 1e-8f);

    const int i = t >> 3, l = t & 7;
    float ai0 = acur[i][0], ai1 = acur[i][1], ai2 = acur[i][2];
    float ai3 = acur[i][3], ai4 = acur[i][4], ai5 = acur[i][5];
    float ks0=0,ks1=0,ks2=0,ks3=0,ks4=0,ks5=0;
    float kx0=0,kx1=0,kx2=0,kx3=0,kx4=0,kx5=0;
    float krow=0.f, kd2=0.f, kxs=0.f;
    #pragma unroll
    for (int jj = 0; jj < 4; ++jj) {
      int j = l + 8 * jj;
      float aj0 = acur[j][0], aj1 = acur[j][1], aj2 = acur[j][2];
      float aj3 = acur[j][3], aj4 = acur[j][4], aj5 = acur[j][5];
      float dv = 0.f, df;
      df = ai0 - aj0; dv += df * df;
      df = ai1 - aj1; dv += df * df;
      df = ai2 - aj2; dv += df * df;
      df = ai3 - aj3; dv += df * df;
      df = ai4 - aj4; dv += df * df;
      df = ai5 - aj5; dv += df * df;
      float kv = expf(-g * dv);
      krow += kv; kd2 += kv * dv; kxs += kv * XSsh[j];
      ks0 += kv * Svv[j][0]; kx0 += kv * aj0;
      ks1 += kv * Svv[j][1]; kx1 += kv * aj1;
      ks2 += kv * Svv[j][2]; kx2 += kv * aj2;
      ks3 += kv * Svv[j][3]; kx3 += kv * aj3;
      ks4 += kv * Svv[j][4]; kx4 += kv * aj4;
      ks5 += kv * Svv[j][5]; kx5 += kv * aj5;
    }
    #pragma unroll
    for (int off = 4; off > 0; off >>= 1) {
      krow += __shfl_down(krow, off, 8);
      kd2  += __shfl_down(kd2,  off, 8);
      kxs  += __shfl_down(kxs,  off, 8);
      ks0 += __shfl_down(ks0, off, 8); kx0 += __shfl_down(kx0, off, 8);
      ks1 += __shfl_down(ks1, off, 8); kx1 += __shfl_down(kx1, off, 8);
      ks2 += __shfl_down(ks2, off, 8); kx2 += __shfl_down(kx2, off, 8);
      ks3 += __shfl_down(ks3, off, 8); kx3 += __shfl_down(kx3, off, 8);
      ks4 += __shfl_down(ks4, off, 8); kx4 += __shfl_down(kx4, off, 8);
      ks5 += __shfl_down(ks5, off, 8); kx5 += __shfl_down(kx5, off, 8);
    }
    float an0=0,an1=0,an2=0,an3=0,an4=0,an5=0, lpnew=0;
    if (l == 0) {
      const float inv_n = 1.0f / 32.0f;
      float t1sum = 0.f, p;
      p = (ks0 + 2.f*g*(ai0*krow - kx0)) * inv_n; an0 = ai0 + LR * p; t1sum += ai0 * ks0;
      p = (ks1 + 2.f*g*(ai1*krow - kx1)) * inv_n; an1 = ai1 + LR * p; t1sum += ai1 * ks1;
      p = (ks2 + 2.f*g*(ai2*krow - kx2)) * inv_n; an2 = ai2 + LR * p; t1sum += ai2 * ks2;
      p = (ks3 + 2.f*g*(ai3*krow - kx3)) * inv_n; an3 = ai3 + LR * p; t1sum += ai3 * ks3;
      p = (ks4 + 2.f*g*(ai4*krow - kx4)) * inv_n; an4 = ai4 + LR * p; t1sum += ai4 * ks4;
      p = (ks5 + 2.f*g*(ai5*krow - kx5)) * inv_n; an5 = ai5 + LR * p; t1sum += ai5 * ks5;
      float term1 = (-2.f * g / 31.f) * (t1sum - kxs);
      float term2 = (-2.f * g / 31.f) * (2.f * g * kd2 - 6.f * (krow - 1.f));
      lpnew = logps[i] - LR * (term1 + term2);
    }
    __syncthreads();  // B10
    if (l == 0) {
      acur[i][0] = an0; acur[i][1] = an1; acur[i][2] = an2;
      acur[i][3] = an3; acur[i][4] = an4; acur[i][5] = an5;
      logps[i] = lpnew;
      xsm[i][17] = f2bf(an0); xsm[i][18] = f2bf(an1); xsm[i][19] = f2bf(an2);
      xsm[i][20] = f2bf(an3); xsm[i][21] = f2bf(an4); xsm[i][22] = f2bf(an5);
    }
    __syncthreads();  // B11
  }

  // ================= epilogue =================
  if (t < 192) { int r = t / 6, d = t - r * 6; out[abase + t] = tanhf(acur[r][d]); }
  if (t < 32) {
    float st = 0.f;
    #pragma unroll
    for (int d = 0; d < 6; ++d) {
      float x = acur[t][d];
      float z = -2.f * x;
      float sp = fmaxf(z, 0.f) + log1pf(expf(-fabsf(z)));
      st += 2.f * (0.69314718056f - x - sp);
    }
    float lpn = -3.0f * logf(1.88495559215f) - (0.5f / 0.3f) * asq[t];
    XSsh[t] = lpn + logps[t] - st;
  }
  __syncthreads();
  if (t == 0) {
    float s = 0.f;
    #pragma unroll
    for (int n = 0; n < 32; ++n) s += XSsh[n];
    out[196608 + b] = s * (1.0f / 32.0f);
  }
}

extern "C" void kernel_launch(void* const* d_in, const int* in_sizes, int n_in,
                              void* d_out, int out_size, void* d_ws, size_t ws_size,
                              hipStream_t stream) {
  const float* obs  = (const float*)d_in[0];
  const float* a0   = (const float*)d_in[1];
  const float* q1W1 = (const float*)d_in[2];
  const float* q1b1 = (const float*)d_in[3];
  const float* q1W2 = (const float*)d_in[4];
  const float* q1b2 = (const float*)d_in[5];
  const float* q1W3 = (const float*)d_in[6];
  const float* q1b3 = (const float*)d_in[7];
  const float* q2W1 = (const float*)d_in[8];
  const float* q2b1 = (const float*)d_in[9];
  const float* q2W2 = (const float*)d_in[10];
  const float* q2b2 = (const float*)d_in[11];
  const float* q2W3 = (const float*)d_in[12];
  const float* q2b3 = (const float*)d_in[13];

  unsigned short* wsu = (unsigned short*)d_ws;
  unsigned short* W2bfA  = wsu;
  unsigned short* W2bfB  = W2bfA + 65536;
  unsigned short* W2TbfA = W2bfB + 65536;
  unsigned short* W2TbfB = W2TbfA + 65536;
  unsigned short* W1TbfA = W2TbfB + 65536;
  unsigned short* W1TbfB = W1TbfA + 8192;
  unsigned short* W1tailA = W1TbfB + 8192;
  unsigned short* W1tailB = W1tailA + 4096;
  float* out  = (float*)d_out;

  prep_kernel<<<1120, 256, 0, stream>>>(q1W1, q2W1, q1W2, q2W2,
      W2bfA, W2bfB, W2TbfA, W2TbfB, W1TbfA, W1TbfB, W1tailA, W1tailB);

  fused_kernel<<<1024, 256, 0, stream>>>(obs, a0,
      q1b1, q1b2, q1W3, q1b3,
      q2b1, q2b2, q2W3, q2b3,
      W2bfA, W2bfB, W2TbfA, W2TbfB, W1TbfA, W1TbfB, W1tailA, W1tailB,
      out);
}

// Round 6
// 305.869 us; speedup vs baseline: 1.5107x; 1.0543x over previous
//
#include <hip/hip_runtime.h>
#include <math.h>

#define LR 0.05f

typedef __attribute__((ext_vector_type(8))) short short8;
typedef __attribute__((ext_vector_type(4))) float f32x4;

#define MFMA16(a, b, c) __builtin_amdgcn_mfma_f32_16x16x32_bf16(a, b, c, 0, 0, 0)

__device__ __forceinline__ unsigned short f2bf(float v) {
  unsigned int u = __float_as_uint(v);
  u += 0x7fffu + ((u >> 16) & 1u);
  return (unsigned short)(u >> 16);
}

__device__ __forceinline__ void ce2(float& a, float& b, bool asc) {
  float lo = fminf(a, b), hi = fmaxf(a, b);
  a = asc ? lo : hi; b = asc ? hi : lo;
}

// ---------------- prep: build FRAGMENT-ORDERED bf16 weight copies ------------
// All B-operand tiles stored so one wave-load = one contiguous 1KB block:
//   frag[tile*512 + l16*32 + quad*8 + e]  (tile = ct*K + k)
__global__ __launch_bounds__(256) void prep_kernel(
    const float* __restrict__ W1a, const float* __restrict__ W1b,
    const float* __restrict__ W2a, const float* __restrict__ W2b,
    unsigned short* __restrict__ W2bfA, unsigned short* __restrict__ W2bfB,
    unsigned short* __restrict__ W2TbfA, unsigned short* __restrict__ W2TbfB,
    unsigned short* __restrict__ W1TbfA, unsigned short* __restrict__ W1TbfB,
    unsigned short* __restrict__ W1tailA, unsigned short* __restrict__ W1tailB)
{
  int i = blockIdx.x * 256 + threadIdx.x;
  if (i < 131072) {
    const float* W2 = (i >> 16) ? W2b : W2a;
    unsigned short* o = (i >> 16) ? W2bfB : W2bfA;
    int j = i & 65535;
    int tile = j >> 9, within = j & 511;
    int l16 = within >> 5, rem = within & 31;
    int ct = tile >> 3, k = tile & 7;
    o[j] = f2bf(W2[(ct * 16 + l16) * 256 + k * 32 + rem]);
  } else if (i < 262144) {
    int i2 = i - 131072;
    const float* W2 = (i2 >> 16) ? W2b : W2a;
    unsigned short* o = (i2 >> 16) ? W2TbfB : W2TbfA;
    int j = i2 & 65535;
    int tile = j >> 9, within = j & 511;
    int l16 = within >> 5, rem = within & 31;
    int ct = tile >> 3, k = tile & 7;
    o[j] = f2bf(W2[(k * 32 + rem) * 256 + ct * 16 + l16]);
  } else if (i < 278528) {
    int i2 = i - 262144;
    const float* W1 = (i2 >> 13) ? W1b : W1a;
    unsigned short* o = (i2 >> 13) ? W1TbfB : W1TbfA;
    int j = i2 & 8191;
    int ct = j >> 9, within = j & 511;
    int l16 = within >> 5, rem = within & 31;
    o[j] = (rem < 23) ? f2bf(W1[rem * 256 + ct * 16 + l16]) : (unsigned short)0;
  } else if (i < 286720) {
    int i2 = i - 278528;
    const float* W1 = (i2 >> 12) ? W1b : W1a;
    unsigned short* o = (i2 >> 12) ? W1tailB : W1tailA;
    int j = i2 & 4095;
    int k = j >> 9, within = j & 511;
    int l16 = within >> 5, rem = within & 31;
    o[j] = (l16 < 6) ? f2bf(W1[(17 + l16) * 256 + k * 32 + rem]) : (unsigned short)0;
  }
}

// ---------------- fused: 5 x (score + SVGD) + epilogue, 2 batches per block --
// R5: L2-latency-bound on weight streaming (R4 analysis). 64-row blocks:
// 512 thr / 8 waves, grid 512, 2 blocks/CU (LDS 80.9KB), 16 waves/CU (same).
// Each wave: 2 col-tiles x 4 row-tiles -> every weight tile loaded ONCE per
// block for 64 rows => per-particle weight traffic halved. Acc <=16 regs
// everywhere (bwd: net selected by disjoint masked writes, 4 passes).
__global__ __launch_bounds__(512, 4) void fused_kernel(
    const float* __restrict__ obs, const float* __restrict__ a0,
    const float* __restrict__ b1a, const float* __restrict__ b2a,
    const float* __restrict__ W3a, const float* __restrict__ b3a,
    const float* __restrict__ b1b, const float* __restrict__ b2b,
    const float* __restrict__ W3b, const float* __restrict__ b3b,
    const unsigned short* __restrict__ W2bfA, const unsigned short* __restrict__ W2bfB,
    const unsigned short* __restrict__ W2TbfA, const unsigned short* __restrict__ W2TbfB,
    const unsigned short* __restrict__ W1TbfA, const unsigned short* __restrict__ W1TbfB,
    const unsigned short* __restrict__ W1tailA, const unsigned short* __restrict__ W1tailB,
    float* __restrict__ out)
{
  __shared__ __align__(16) unsigned short buf0[64][264];  // h1a -> dh2c; sort alias
  __shared__ __align__(16) unsigned short buf1[64][264];  // h1b -> dh1_m
  __shared__ __align__(16) unsigned short xsm[64][40];    // bf16 x (obs cols persist)
  __shared__ __align__(16) float upool[1024];             // qpart[2][8][64] | redS[128][6]
  __shared__ float acur[64][6];
  __shared__ float Svv[64][6];
  __shared__ float XSsh[64];
  __shared__ float logps[64];
  __shared__ float asq[64];
  __shared__ int   selsh[64];
  __shared__ float medsh[2][2];

  float (*qpart)[8][64] = (float (*)[8][64])upool;
  float (*redS)[6] = (float (*)[6])upool;

  const int t = threadIdx.x;
  const int lane = t & 63, wv = t >> 6, quad = lane >> 4, l16 = lane & 15;
  const int b = blockIdx.x;
  const long abase = (long)b * 384;          // a0/out base (2 batches)
  const int wfrag = l16 * 32 + quad * 8;     // lane's short-offset within a 1KB tile
  const int bq = t >> 8;                     // batch half for sort/K phases
  const int tq = t & 255;                    // thread index within batch group
  const int eb = tq * 2;                     // this thread's 2 sort elements
  const int abq = bq * 32;                   // acur row base of this thread's batch

  float* sortA = (float*)&buf0[0][0] + bq * 1024;  // 512 floats per batch
  float* sortB = sortA + 512;

  // triangular index map for sort elements 2tq, 2tq+1 (step-invariant, packed)
  int packij = 0;
  {
    #pragma unroll
    for (int m = 0; m < 2; ++m) {
      int e = eb + m;
      int ii = 0, jj = 0;
      if (e < 496) {
        float sq = sqrtf(992.25f - 2.0f * (float)e);
        ii = (int)(31.5f - sq);
        if (e >= ((ii + 1) * (62 - ii)) / 2) ++ii;
        else if (e < (ii * (63 - ii)) / 2) --ii;
        jj = ii + 1 + (e - (ii * (63 - ii)) / 2);
      }
      packij |= (ii | (jj << 5)) << (m * 10);
    }
  }

  // ---- init ----
  if (t < 384) { int r = t / 6, d = t - r * 6; acur[r][d] = a0[abase + t]; }
  if (t < 64) {
    float s = 0.f;
    #pragma unroll
    for (int d = 0; d < 6; ++d) { float x0 = a0[abase + t * 6 + d]; s += x0 * x0; }
    asq[t] = s; logps[t] = 0.f;
  }
  for (int idx = t; idx < 64 * 40; idx += 512) {
    int r = idx / 40, k = idx - r * 40;
    float v = 0.f;
    if (k < 17) v = obs[((long)b * 64 + r) * 17 + k];
    else if (k < 23) v = a0[abase + r * 6 + (k - 17)];
    xsm[r][k] = f2bf(v);
  }
  __syncthreads();

  #pragma unroll 1
  for (int s = 0; s < 5; ++s) {
    // ---- sort element values (regs) from acur (per-batch triangle) ----
    float sv0 = 0.f, sv1 = 0.f;
    {
      int i0 = (packij & 31) + abq, j0 = ((packij >> 5) & 31) + abq;
      int i1 = ((packij >> 10) & 31) + abq, j1 = ((packij >> 15) & 31) + abq;
      #pragma unroll
      for (int d = 0; d < 6; ++d) {
        float d0 = acur[i0][d] - acur[j0][d]; sv0 += d0 * d0;
        float d1 = acur[i1][d] - acur[j1][d]; sv1 += d1 * d1;
      }
    }

    // ================= h1 both nets (wave: 2 col-tiles x 4 row-tiles) =======
    unsigned int m1a_bits = 0, m1b_bits = 0, m2a_bits = 0, m2b_bits = 0;
    {
      short8 ax[4];
      #pragma unroll
      for (int rt = 0; rt < 4; ++rt)
        ax[rt] = *(const short8*)&xsm[rt * 16 + l16][quad * 8];
      #pragma unroll 1
      for (int net = 0; net < 2; ++net) {
        const unsigned short* W1T = net ? W1TbfB : W1TbfA;
        const float* b1 = net ? b1b : b1a;
        unsigned short (*hbuf)[264] = net ? buf1 : buf0;
        unsigned int m1 = 0;
        #pragma unroll
        for (int c = 0; c < 2; ++c) {
          int ct = wv * 2 + c;
          short8 bw = *(const short8*)&W1T[ct * 512 + wfrag];
          int col = ct * 16 + l16;
          float b1v = b1[col];
          #pragma unroll
          for (int rt = 0; rt < 4; ++rt) {
            f32x4 z = {0.f, 0.f, 0.f, 0.f};
            f32x4 h = MFMA16(ax[rt], bw, z);
            #pragma unroll
            for (int g = 0; g < 4; ++g) {
              float v = h[g] + b1v;
              if (v > 0.f) m1 |= 1u << ((rt * 2 + c) * 4 + g);
              hbuf[rt * 16 + quad * 4 + g][col] = (v > 0.f) ? f2bf(v) : (unsigned short)0;
            }
          }
        }
        if (net) m1b_bits = m1; else m1a_bits = m1;
      }
    }
    __syncthreads();  // B1

    // ================= h2 both nets + qpart (per-col passes, acc[4]) ========
    #pragma unroll 1
    for (int net = 0; net < 2; ++net) {
      const unsigned short* W2T = net ? W2TbfB : W2TbfA;
      const float* b2 = net ? b2b : b2a;
      const float* W3 = net ? W3b : W3a;
      unsigned short (*hbuf)[264] = net ? buf1 : buf0;

      float pq[4][4];
      #pragma unroll
      for (int rt = 0; rt < 4; ++rt)
        #pragma unroll
        for (int g = 0; g < 4; ++g) pq[rt][g] = 0.f;
      unsigned int m2 = 0;

      #pragma unroll 1
      for (int c = 0; c < 2; ++c) {
        int ct = wv * 2 + c;
        f32x4 acc[4];
        acc[0] = acc[1] = acc[2] = acc[3] = (f32x4){0.f, 0.f, 0.f, 0.f};
        #pragma unroll 1
        for (int k = 0; k < 8; ++k) {
          short8 bw = *(const short8*)&W2T[ct * 4096 + k * 512 + wfrag];
          #pragma unroll
          for (int rt = 0; rt < 4; ++rt) {
            short8 af = *(const short8*)&hbuf[rt * 16 + l16][k * 32 + quad * 8];
            acc[rt] = MFMA16(af, bw, acc[rt]);
          }
        }
        int col = ct * 16 + l16;
        float b2v = b2[col], w3v = W3[col];
        #pragma unroll
        for (int rt = 0; rt < 4; ++rt)
          #pragma unroll
          for (int g = 0; g < 4; ++g) {
            float v = acc[rt][g] + b2v;
            if (v > 0.f) {
              m2 |= 1u << ((rt * 2 + c) * 4 + g);
              pq[rt][g] += v * w3v;
            }
          }
      }
      if (net) m2b_bits = m2; else m2a_bits = m2;
      #pragma unroll
      for (int off = 8; off; off >>= 1) {
        #pragma unroll
        for (int rt = 0; rt < 4; ++rt)
          #pragma unroll
          for (int g = 0; g < 4; ++g)
            pq[rt][g] += __shfl_xor(pq[rt][g], off, 16);
      }
      if (l16 == 0) {
        #pragma unroll
        for (int rt = 0; rt < 4; ++rt)
          #pragma unroll
          for (int g = 0; g < 4; ++g)
            qpart[net][wv][rt * 16 + quad * 4 + g] = pq[rt][g];
      }
    }
    __syncthreads();  // B2

    // ---- sel (t<64) + intra-wave sort k=2..128 (barrier bubble filler) ----
    if (t < 64) {
      float qa = b3a[0], qb = b3b[0];
      #pragma unroll
      for (int w = 0; w < 8; ++w) { qa += qpart[0][w][t]; qb += qpart[1][w][t]; }
      selsh[t] = (qa <= qb) ? 0 : 1;
    }
    #pragma unroll
    for (int k = 2; k <= 128; k <<= 1) {
      #pragma unroll
      for (int j = k >> 1; j >= 2; j >>= 1) {
        int lm = j >> 1;
        bool km = (((eb & j) == 0) == ((eb & k) == 0));
        float p0 = __shfl_xor(sv0, lm);
        sv0 = km ? fminf(sv0, p0) : fmaxf(sv0, p0);
        float p1 = __shfl_xor(sv1, lm);
        sv1 = km ? fminf(sv1, p1) : fmaxf(sv1, p1);
      }
      ce2(sv0, sv1, ((eb & k) == 0));
    }
    __syncthreads();  // B3

    // ---- dh2c: single buffer, selected net only ----
    #pragma unroll
    for (int c = 0; c < 2; ++c) {
      int col = (wv * 2 + c) * 16 + l16;
      unsigned short w3abf = f2bf(W3a[col]);
      unsigned short w3bbf = f2bf(W3b[col]);
      #pragma unroll
      for (int rt = 0; rt < 4; ++rt)
        #pragma unroll
        for (int g = 0; g < 4; ++g) {
          int row = rt * 16 + quad * 4 + g;
          int sl = selsh[row];
          int bit = (rt * 2 + c) * 4 + g;
          unsigned int mb = sl ? m2b_bits : m2a_bits;
          unsigned short wv3 = sl ? w3bbf : w3abf;
          buf0[row][col] = ((mb >> bit) & 1) ? wv3 : (unsigned short)0;
        }
    }
    __syncthreads();  // B4

    // ---- bwd: 4 passes (net x col); disjoint masked writes -> buf1 ----
    #pragma unroll 1
    for (int pass = 0; pass < 4; ++pass) {
      int net = pass >> 1, c = pass & 1;
      int ct = wv * 2 + c;
      const unsigned short* W2f = net ? W2bfB : W2bfA;
      f32x4 acc[4];
      acc[0] = acc[1] = acc[2] = acc[3] = (f32x4){0.f, 0.f, 0.f, 0.f};
      #pragma unroll 1
      for (int k = 0; k < 8; ++k) {
        short8 bw = *(const short8*)&W2f[ct * 4096 + k * 512 + wfrag];
        #pragma unroll
        for (int rt = 0; rt < 4; ++rt) {
          short8 ad = *(const short8*)&buf0[rt * 16 + l16][k * 32 + quad * 8];
          acc[rt] = MFMA16(ad, bw, acc[rt]);
        }
      }
      int col = ct * 16 + l16;
      unsigned int mb = net ? m1b_bits : m1a_bits;
      #pragma unroll
      for (int rt = 0; rt < 4; ++rt)
        #pragma unroll
        for (int g = 0; g < 4; ++g) {
          int row = rt * 16 + quad * 4 + g;
          if (selsh[row] == net) {
            int bit = (rt * 2 + c) * 4 + g;
            buf1[row][col] = ((mb >> bit) & 1) ? f2bf(acc[rt][g]) : (unsigned short)0;
          }
        }
    }
    __syncthreads();  // B5

    // ---- S (wave: net = wv>>2, rt = wv&3) + sort stage1 write (buf0 dead) --
    {
      int net = wv >> 2, rt = wv & 3;
      const unsigned short* Wt = net ? W1tailB : W1tailA;
      f32x4 sacc = {0.f, 0.f, 0.f, 0.f};
      #pragma unroll 1
      for (int k = 0; k < 8; ++k) {
        short8 a = *(const short8*)&buf1[rt * 16 + l16][k * 32 + quad * 8];
        short8 bb2 = *(const short8*)&Wt[k * 512 + wfrag];
        sacc = MFMA16(a, bb2, sacc);
      }
      if (l16 < 6) {
        #pragma unroll
        for (int g = 0; g < 4; ++g)
          redS[net * 64 + rt * 16 + quad * 4 + g][l16] = sacc[g];
      }
    }
    sortA[eb] = sv0; sortA[eb + 1] = sv1;
    __syncthreads();  // B6

    // ---- sort stage1 read (k=256, j=128) + tail + Svv fill + stage2 write --
    {
      bool km = (((eb & 128) == 0) == ((eb & 256) == 0));
      float p0 = sortA[eb ^ 128];
      float p1 = sortA[(eb ^ 128) + 1];
      sv0 = km ? fminf(sv0, p0) : fmaxf(sv0, p0);
      sv1 = km ? fminf(sv1, p1) : fmaxf(sv1, p1);
      #pragma unroll
      for (int j = 64; j >= 2; j >>= 1) {
        int lm = j >> 1;
        bool k2 = (((eb & j) == 0) == ((eb & 256) == 0));
        float q0 = __shfl_xor(sv0, lm);
        sv0 = k2 ? fminf(sv0, q0) : fmaxf(sv0, q0);
        float q1 = __shfl_xor(sv1, lm);
        sv1 = k2 ? fminf(sv1, q1) : fmaxf(sv1, q1);
      }
      ce2(sv0, sv1, ((eb & 256) == 0));
    }
    if (t < 384) { int r = t / 6, d = t - r * 6; Svv[r][d] = redS[selsh[r] * 64 + r][d]; }
    sortB[eb] = sv0; sortB[eb + 1] = sv1;
    __syncthreads();  // B7

    // ---- sort stage2 read (k=512, j=256) + XSsh + stage3 write ----
    {
      bool km = ((eb & 256) == 0);
      float p0 = sortB[eb ^ 256];
      float p1 = sortB[(eb ^ 256) + 1];
      sv0 = km ? fminf(sv0, p0) : fmaxf(sv0, p0);
      sv1 = km ? fminf(sv1, p1) : fmaxf(sv1, p1);
    }
    if (t < 64) {
      float sx = 0.f;
      #pragma unroll
      for (int d = 0; d < 6; ++d) sx += acur[t][d] * Svv[t][d];
      XSsh[t] = sx;
    }
    sortA[eb] = sv0; sortA[eb + 1] = sv1;
    __syncthreads();  // B8

    // ---- sort stage3 read (j=128) + final tail + median ----
    {
      bool km = ((eb & 128) == 0);
      float p0 = sortA[eb ^ 128];
      float p1 = sortA[(eb ^ 128) + 1];
      sv0 = km ? fminf(sv0, p0) : fmaxf(sv0, p0);
      sv1 = km ? fminf(sv1, p1) : fmaxf(sv1, p1);
      #pragma unroll
      for (int j = 64; j >= 2; j >>= 1) {
        int lm = j >> 1;
        bool k2 = ((eb & j) == 0);
        float q0 = __shfl_xor(sv0, lm);
        sv0 = k2 ? fminf(sv0, q0) : fmaxf(sv0, q0);
        float q1 = __shfl_xor(sv1, lm);
        sv1 = k2 ? fminf(sv1, q1) : fmaxf(sv1, q1);
      }
      ce2(sv0, sv1, true);
    }
    if (tq == 127) medsh[bq][0] = sv1;  // element 255 of this batch
    if (tq == 128) medsh[bq][1] = sv0;  // element 256 of this batch
    __syncthreads();  // B9

    // ================= K row-sums + update (dv recomputed from acur) ========
    float med = 0.5f * (medsh[bq][0] + medsh[bq][1]);
    float g = 1.0f / (2.0f * (med / logf(33.0f)) + 1e-8f);

    const int i = t >> 3, l = t & 7;   // i in [0,64); batch of row i = i>>5 = bq
    const int jb = i & 32;             // batch row base
    float ai0 = acur[i][0], ai1 = acur[i][1], ai2 = acur[i][2];
    float ai3 = acur[i][3], ai4 = acur[i][4], ai5 = acur[i][5];
    float ks0=0,ks1=0,ks2=0,ks3=0,ks4=0,ks5=0;
    float kx0=0,kx1=0,kx2=0,kx3=0,kx4=0,kx5=0;
    float krow=0.f, kd2=0.f, kxs=0.f;
    #pragma unroll
    for (int jj = 0; jj < 4; ++jj) {
      int j = jb + l + 8 * jj;
      float aj0 = acur[j][0], aj1 = acur[j][1], aj2 = acur[j][2];
      float aj3 = acur[j][3], aj4 = acur[j][4], aj5 = acur[j][5];
      float dv = 0.f, df;
      df = ai0 - aj0; dv += df * df;
      df = ai1 - aj1; dv += df * df;
      df = ai2 - aj2; dv += df * df;
      df = ai3 - aj3; dv += df * df;
      df = ai4 - aj4; dv += df * df;
      df = ai5 - aj5; dv += df * df;
      float kv = expf(-g * dv);
      krow += kv; kd2 += kv * dv; kxs += kv * XSsh[j];
      ks0 += kv * Svv[j][0]; kx0 += kv * aj0;
      ks1 += kv * Svv[j][1]; kx1 += kv * aj1;
      ks2 += kv * Svv[j][2]; kx2 += kv * aj2;
      ks3 += kv * Svv[j][3]; kx3 += kv * aj3;
      ks4 += kv * Svv[j][4]; kx4 += kv * aj4;
      ks5 += kv * Svv[j][5]; kx5 += kv * aj5;
    }
    #pragma unroll
    for (int off = 4; off > 0; off >>= 1) {
      krow += __shfl_down(krow, off, 8);
      kd2  += __shfl_down(kd2,  off, 8);
      kxs  += __shfl_down(kxs,  off, 8);
      ks0 += __shfl_down(ks0, off, 8); kx0 += __shfl_down(kx0, off, 8);
      ks1 += __shfl_down(ks1, off, 8); kx1 += __shfl_down(kx1, off, 8);
      ks2 += __shfl_down(ks2, off, 8); kx2 += __shfl_down(kx2, off, 8);
      ks3 += __shfl_down(ks3, off, 8); kx3 += __shfl_down(kx3, off, 8);
      ks4 += __shfl_down(ks4, off, 8); kx4 += __shfl_down(kx4, off, 8);
      ks5 += __shfl_down(ks5, off, 8); kx5 += __shfl_down(kx5, off, 8);
    }
    float an0=0,an1=0,an2=0,an3=0,an4=0,an5=0, lpnew=0;
    if (l == 0) {
      const float inv_n = 1.0f / 32.0f;
      float t1sum = 0.f, p;
      p = (ks0 + 2.f*g*(ai0*krow - kx0)) * inv_n; an0 = ai0 + LR * p; t1sum += ai0 * ks0;
      p = (ks1 + 2.f*g*(ai1*krow - kx1)) * inv_n; an1 = ai1 + LR * p; t1sum += ai1 * ks1;
      p = (ks2 + 2.f*g*(ai2*krow - kx2)) * inv_n; an2 = ai2 + LR * p; t1sum += ai2 * ks2;
      p = (ks3 + 2.f*g*(ai3*krow - kx3)) * inv_n; an3 = ai3 + LR * p; t1sum += ai3 * ks3;
      p = (ks4 + 2.f*g*(ai4*krow - kx4)) * inv_n; an4 = ai4 + LR * p; t1sum += ai4 * ks4;
      p = (ks5 + 2.f*g*(ai5*krow - kx5)) * inv_n; an5 = ai5 + LR * p; t1sum += ai5 * ks5;
      float term1 = (-2.f * g / 31.f) * (t1sum - kxs);
      float term2 = (-2.f * g / 31.f) * (2.f * g * kd2 - 6.f * (krow - 1.f));
      lpnew = logps[i] - LR * (term1 + term2);
    }
    __syncthreads();  // B10
    if (l == 0) {
      acur[i][0] = an0; acur[i][1] = an1; acur[i][2] = an2;
      acur[i][3] = an3; acur[i][4] = an4; acur[i][5] = an5;
      logps[i] = lpnew;
      xsm[i][17] = f2bf(an0); xsm[i][18] = f2bf(an1); xsm[i][19] = f2bf(an2);
      xsm[i][20] = f2bf(an3); xsm[i][21] = f2bf(an4); xsm[i][22] = f2bf(an5);
    }
    __syncthreads();  // B11
  }

  // ================= epilogue =================
  if (t < 384) { int r = t / 6, d = t - r * 6; out[abase + t] = tanhf(acur[r][d]); }
  if (t < 64) {
    float st = 0.f;
    #pragma unroll
    for (int d = 0; d < 6; ++d) {
      float x = acur[t][d];
      float z = -2.f * x;
      float sp = fmaxf(z, 0.f) + log1pf(expf(-fabsf(z)));
      st += 2.f * (0.69314718056f - x - sp);
    }
    float lpn = -3.0f * logf(1.88495559215f) - (0.5f / 0.3f) * asq[t];
    XSsh[t] = lpn + logps[t] - st;
  }
  __syncthreads();
  if (tq == 0) {
    float s = 0.f;
    #pragma unroll
    for (int n = 0; n < 32; ++n) s += XSsh[bq * 32 + n];
    out[196608 + 2 * b + bq] = s * (1.0f / 32.0f);
  }
}

extern "C" void kernel_launch(void* const* d_in, const int* in_sizes, int n_in,
                              void* d_out, int out_size, void* d_ws, size_t ws_size,
                              hipStream_t stream) {
  const float* obs  = (const float*)d_in[0];
  const float* a0   = (const float*)d_in[1];
  const float* q1W1 = (const float*)d_in[2];
  const float* q1b1 = (const float*)d_in[3];
  const float* q1W2 = (const float*)d_in[4];
  const float* q1b2 = (const float*)d_in[5];
  const float* q1W3 = (const float*)d_in[6];
  const float* q1b3 = (const float*)d_in[7];
  const float* q2W1 = (const float*)d_in[8];
  const float* q2b1 = (const float*)d_in[9];
  const float* q2W2 = (const float*)d_in[10];
  const float* q2b2 = (const float*)d_in[11];
  const float* q2W3 = (const float*)d_in[12];
  const float* q2b3 = (const float*)d_in[13];

  unsigned short* wsu = (unsigned short*)d_ws;
  unsigned short* W2bfA  = wsu;
  unsigned short* W2bfB  = W2bfA + 65536;
  unsigned short* W2TbfA = W2bfB + 65536;
  unsigned short* W2TbfB = W2TbfA + 65536;
  unsigned short* W1TbfA = W2TbfB + 65536;
  unsigned short* W1TbfB = W1TbfA + 8192;
  unsigned short* W1tailA = W1TbfB + 8192;
  unsigned short* W1tailB = W1tailA + 4096;
  float* out  = (float*)d_out;

  prep_kernel<<<1120, 256, 0, stream>>>(q1W1, q2W1, q1W2, q2W2,
      W2bfA, W2bfB, W2TbfA, W2TbfB, W1TbfA, W1TbfB, W1tailA, W1tailB);

  fused_kernel<<<512, 512, 0, stream>>>(obs, a0,
      q1b1, q1b2, q1W3, q1b3,
      q2b1, q2b2, q2W3, q2b3,
      W2bfA, W2bfB, W2TbfA, W2TbfB, W1TbfA, W1TbfB, W1tailA, W1tailB,
      out);
}